// Round 2
// baseline (6043.390 us; speedup 1.0000x reference)
//
#include <hip/hip_runtime.h>
#include <hip/hip_bf16.h>
#include <cstdint>
#include <cstddef>

#define BATCH 512
#define SEQL 256
#define DIN 256
#define HID 128
#define OUTD 256
#define G3 384            // 3*H
#define TCH 32            // time chunk
#define NCH 8             // SEQL / TCH
#define MTOT (BATCH*SEQL) // 131072
#define MCH  (BATCH*TCH)  // 16384 rows per chunk per dir

__device__ __forceinline__ float sigmoidf_(float x) {
  return 1.0f / (1.0f + expf(-x));
}

// ---- K1: chunked input GEMM: gates = X_chunk @ Wih^T + bih (fwd chunk cF, bwd chunk cB) ----
// grid (MCH/128, 6): y<3 -> fwd N-tile, y>=3 -> bwd N-tile. 128x128 tile, BK=16, 8x8/thread.
__global__ __launch_bounds__(256) void gx_gemm_chunk(
    const float* __restrict__ X,
    const float* __restrict__ Wf, const float* __restrict__ Wb,
    const float* __restrict__ bf, const float* __restrict__ bb,
    float* __restrict__ bufF, float* __restrict__ bufB, int cF, int cB)
{
  __shared__ float As[16][132];
  __shared__ float Bs[16][132];
  const int tid = threadIdx.x;
  const int m0  = blockIdx.x * 128;   // row in [0, MCH)
  int yy = blockIdx.y;
  const float* W; const float* bias; float* buf; int c;
  if (yy < 3) { W = Wf; bias = bf; buf = bufF; c = cF; }
  else        { yy -= 3; W = Wb; bias = bb; buf = bufB; c = cB; }
  const int n0 = yy * 128;

  const int lk = tid & 15;
  const int lr = tid >> 4;
  const int tr = tid >> 4;
  const int tc = tid & 15;

  float acc[8][8];
#pragma unroll
  for (int i = 0; i < 8; i++)
#pragma unroll
    for (int j = 0; j < 8; j++) acc[i][j] = 0.0f;

  for (int kt = 0; kt < DIN; kt += 16) {
#pragma unroll
    for (int i = 0; i < 8; i++) {
      int ml = lr + i * 16;
      int r  = m0 + ml;                 // chunk-row
      int bb_ = r >> 5;                 // batch
      int tt  = r & 31;                 // t within chunk
      int xrow = bb_ * SEQL + c * TCH + tt;
      As[lk][ml] = X[(size_t)xrow * DIN + kt + lk];
    }
#pragma unroll
    for (int i = 0; i < 8; i++) {
      int nl = lr + i * 16;
      Bs[lk][nl] = W[(size_t)(n0 + nl) * DIN + kt + lk];
    }
    __syncthreads();
#pragma unroll
    for (int kk = 0; kk < 16; kk++) {
      float4 a0 = *(const float4*)&As[kk][tr * 8];
      float4 a1 = *(const float4*)&As[kk][tr * 8 + 4];
      float4 b0 = *(const float4*)&Bs[kk][tc * 8];
      float4 b1 = *(const float4*)&Bs[kk][tc * 8 + 4];
      float a[8] = {a0.x,a0.y,a0.z,a0.w,a1.x,a1.y,a1.z,a1.w};
      float bv[8] = {b0.x,b0.y,b0.z,b0.w,b1.x,b1.y,b1.z,b1.w};
#pragma unroll
      for (int i = 0; i < 8; i++)
#pragma unroll
        for (int j = 0; j < 8; j++) acc[i][j] += a[i] * bv[j];
    }
    __syncthreads();
  }

  float bl[8];
#pragma unroll
  for (int j = 0; j < 8; j++) bl[j] = bias[n0 + tc * 8 + j];
#pragma unroll
  for (int i = 0; i < 8; i++) {
    int r = m0 + tr * 8 + i;
    float* row = buf + (size_t)r * G3 + n0 + tc * 8;
    float4 o0, o1;
    o0.x = acc[i][0] + bl[0]; o0.y = acc[i][1] + bl[1];
    o0.z = acc[i][2] + bl[2]; o0.w = acc[i][3] + bl[3];
    o1.x = acc[i][4] + bl[4]; o1.y = acc[i][5] + bl[5];
    o1.z = acc[i][6] + bl[6]; o1.w = acc[i][7] + bl[7];
    *(float4*)&row[0] = o0;
    *(float4*)&row[4] = o1;
  }
}

// ---- K2: chunked masked GRU scan. blocks 0..511 fwd chunk ci, 512..1023 bwd chunk NCH-1-ci ----
__global__ __launch_bounds__(384) void gru_scan_chunk(
    const int* __restrict__ seqlens,
    const float* __restrict__ Whh_f, const float* __restrict__ Whh_b,
    const float* __restrict__ bhh_f, const float* __restrict__ bhh_b,
    const float* __restrict__ bufF, const float* __restrict__ bufB,
    float* __restrict__ hstate, __hip_bfloat16* __restrict__ rnn, int ci)
{
  const int fwd = (blockIdx.x < BATCH) ? 1 : 0;
  const int b   = fwd ? blockIdx.x : (blockIdx.x - BATCH);
  const int len = seqlens[b];
  const int tid = threadIdx.x;
  const float* Whh = fwd ? Whh_f : Whh_b;
  const float* bhh = fwd ? bhh_f : bhh_b;
  const float* buf = fwd ? bufF : bufB;
  float* hst = hstate + (size_t)(fwd ? b : (BATCH + b)) * HID;
  const int c = fwd ? ci : (NCH - 1 - ci);

  __shared__ float hs[HID];
  __shared__ float ghs[G3];
  if (tid < HID) hs[tid] = (ci == 0) ? 0.0f : hst[tid];
  __syncthreads();

  const float* wrow = Whh + (size_t)tid * HID;
  const float bias = bhh[tid];

  for (int ss = 0; ss < TCH; ++ss) {
    const int tt = fwd ? ss : (TCH - 1 - ss);
    const int t  = c * TCH + tt;
    if (t >= len) { if (fwd) break; else continue; }

    float acc = 0.0f;
#pragma unroll 8
    for (int k4 = 0; k4 < HID / 4; ++k4) {
      float4 w  = *(const float4*)(wrow + k4 * 4);
      float4 h4 = *(const float4*)(&hs[k4 * 4]);
      acc += w.x * h4.x + w.y * h4.y + w.z * h4.z + w.w * h4.w;
    }
    ghs[tid] = acc + bias;
    __syncthreads();
    if (tid < HID) {
      const size_t gbase = (size_t)(b * TCH + tt) * G3 + tid;
      float gxr = buf[gbase];
      float gxz = buf[gbase + HID];
      float gxn = buf[gbase + 2 * HID];
      float r = sigmoidf_(gxr + ghs[tid]);
      float z = sigmoidf_(gxz + ghs[HID + tid]);
      float cand = tanhf(gxn + r * ghs[2 * HID + tid]);
      float hn = (1.0f - z) * cand + z * hs[tid];
      hs[tid] = hn;
      rnn[(size_t)(b * SEQL + t) * OUTD + (fwd ? 0 : HID) + tid] = __float2bfloat16(hn);
    }
    __syncthreads();
  }
  if (tid < HID) hst[tid] = hs[tid];
}

// ---- K3: scores = ctx . tanh(rnn @ Wmlp^T + bmlp), rnn in bf16 ----
__global__ __launch_bounds__(256) void mlp_score(
    const __hip_bfloat16* __restrict__ rnn,
    const float* __restrict__ Wmlp, const float* __restrict__ bmlp,
    const float* __restrict__ ctx,
    float* __restrict__ scores)
{
  __shared__ float As[16][68];
  __shared__ float Bs[16][260];
  const int tid = threadIdx.x;
  const int m0 = blockIdx.x * 64;
  const int lk = tid & 15;
  const int lr = tid >> 4;
  const int tr = tid >> 5;
  const int tc = tid & 31;

  float acc[8][8];
#pragma unroll
  for (int i = 0; i < 8; i++)
#pragma unroll
    for (int j = 0; j < 8; j++) acc[i][j] = 0.0f;

  for (int kt = 0; kt < OUTD; kt += 16) {
#pragma unroll
    for (int i = 0; i < 4; i++) {
      int ml = lr + i * 16;
      As[lk][ml] = __bfloat162float(rnn[(size_t)(m0 + ml) * OUTD + kt + lk]);
    }
#pragma unroll
    for (int i = 0; i < 16; i++) {
      int nl = lr + i * 16;
      Bs[lk][nl] = Wmlp[(size_t)nl * OUTD + kt + lk];
    }
    __syncthreads();
#pragma unroll
    for (int kk = 0; kk < 16; kk++) {
      float4 a0 = *(const float4*)&As[kk][tr * 8];
      float4 a1 = *(const float4*)&As[kk][tr * 8 + 4];
      float4 b0 = *(const float4*)&Bs[kk][tc * 8];
      float4 b1 = *(const float4*)&Bs[kk][tc * 8 + 4];
      float a[8] = {a0.x,a0.y,a0.z,a0.w,a1.x,a1.y,a1.z,a1.w};
      float bv[8] = {b0.x,b0.y,b0.z,b0.w,b1.x,b1.y,b1.z,b1.w};
#pragma unroll
      for (int i = 0; i < 8; i++)
#pragma unroll
        for (int j = 0; j < 8; j++) acc[i][j] += a[i] * bv[j];
    }
    __syncthreads();
  }

  float bl[8], cl[8];
#pragma unroll
  for (int j = 0; j < 8; j++) { bl[j] = bmlp[tc * 8 + j]; cl[j] = ctx[tc * 8 + j]; }

  float part[8];
#pragma unroll
  for (int i = 0; i < 8; i++) {
    float p = 0.0f;
#pragma unroll
    for (int j = 0; j < 8; j++) p += tanhf(acc[i][j] + bl[j]) * cl[j];
    part[i] = p;
  }
#pragma unroll
  for (int off = 16; off > 0; off >>= 1)
#pragma unroll
    for (int i = 0; i < 8; i++) part[i] += __shfl_xor(part[i], off, 64);

  if (tc == 0) {
#pragma unroll
    for (int i = 0; i < 8; i++) scores[m0 + tr * 8 + i] = part[i];
  }
}

// ---- K4: masked softmax over l + weighted pool (rnn bf16 -> out fp32) ----
__global__ __launch_bounds__(256) void softmax_pool(
    const int* __restrict__ seqlens,
    const float* __restrict__ scores,
    const __hip_bfloat16* __restrict__ rnn,
    float* __restrict__ out)
{
  const int b = blockIdx.x;
  const int len = seqlens[b];
  const int tid = threadIdx.x;
  __shared__ float sm[SEQL];
  __shared__ float red[8];

  float s = (tid < len) ? scores[b * SEQL + tid] : -3.4e38f;
  float wm = s;
#pragma unroll
  for (int off = 32; off > 0; off >>= 1) wm = fmaxf(wm, __shfl_xor(wm, off, 64));
  if ((tid & 63) == 0) red[tid >> 6] = wm;
  __syncthreads();
  float bm = fmaxf(fmaxf(red[0], red[1]), fmaxf(red[2], red[3]));

  float e = (tid < len) ? expf(s - bm) : 0.0f;
  sm[tid] = e;
  float sum = e;
#pragma unroll
  for (int off = 32; off > 0; off >>= 1) sum += __shfl_xor(sum, off, 64);
  if ((tid & 63) == 0) red[4 + (tid >> 6)] = sum;
  __syncthreads();
  float inv = 1.0f / (red[4] + red[5] + red[6] + red[7]);

  float acc = 0.0f;
  for (int l = 0; l < len; ++l)
    acc += sm[l] * __bfloat162float(rnn[(size_t)(b * SEQL + l) * OUTD + tid]);
  out[b * OUTD + tid] = acc * inv;
}

extern "C" void kernel_launch(void* const* d_in, const int* in_sizes, int n_in,
                              void* d_out, int out_size, void* d_ws, size_t ws_size,
                              hipStream_t stream) {
  const float* seq    = (const float*)d_in[0];
  const int*   lens   = (const int*)d_in[1];
  const float* Wih_f  = (const float*)d_in[2];
  const float* Whh_f  = (const float*)d_in[3];
  const float* bih_f  = (const float*)d_in[4];
  const float* bhh_f  = (const float*)d_in[5];
  const float* Wih_b  = (const float*)d_in[6];
  const float* Whh_b  = (const float*)d_in[7];
  const float* bih_b  = (const float*)d_in[8];
  const float* bhh_b  = (const float*)d_in[9];
  const float* Wmlp   = (const float*)d_in[10];
  const float* bmlp   = (const float*)d_in[11];
  const float* ctx    = (const float*)d_in[12];
  float* out = (float*)d_out;

  // ws layout:
  //   bufF   MCH*G3 fp32   = 25.2 MB
  //   bufB   MCH*G3 fp32   = 25.2 MB
  //   rnn    MTOT*OUTD bf16 = 67.1 MB
  //   scores MTOT fp32     = 0.5 MB
  //   hstate 2*BATCH*HID fp32 = 0.5 MB   (total ~118.5 MB)
  float* bufF = (float*)d_ws;
  float* bufB = bufF + (size_t)MCH * G3;
  __hip_bfloat16* rnn = (__hip_bfloat16*)(bufB + (size_t)MCH * G3);
  float* scores = (float*)(rnn + (size_t)MTOT * OUTD);
  float* hstate = scores + MTOT;

  dim3 gG(MCH / 128, 6);
  for (int ci = 0; ci < NCH; ++ci) {
    gx_gemm_chunk<<<gG, 256, 0, stream>>>(seq, Wih_f, Wih_b, bih_f, bih_b,
                                          bufF, bufB, ci, NCH - 1 - ci);
    gru_scan_chunk<<<dim3(BATCH * 2), 384, 0, stream>>>(
        lens, Whh_f, Whh_b, bhh_f, bhh_b, bufF, bufB, hstate, rnn, ci);
  }
  mlp_score<<<dim3(MTOT / 64), 256, 0, stream>>>(rnn, Wmlp, bmlp, ctx, scores);
  softmax_pool<<<dim3(BATCH), 256, 0, stream>>>(lens, scores, rnn, out);
}

// Round 3
// 2539.224 us; speedup vs baseline: 2.3800x; 2.3800x over previous
//
#include <hip/hip_runtime.h>
#include <hip/hip_bf16.h>
#include <cstdint>
#include <cstddef>

#define BATCH 512
#define SEQL 256
#define DIN 256
#define HID 128
#define OUTD 256
#define G3 384            // 3*H
#define TCH 32            // time chunk
#define NCH 8             // SEQL / TCH
#define NB 4              // batches per scan block
#define NGRP (BATCH/NB)   // 128 groups per dir
#define MTOT (BATCH*SEQL) // 131072
#define MCH  (BATCH*TCH)  // 16384 rows per chunk per dir

__device__ __forceinline__ float sigmoidf_(float x) {
  return 1.0f / (1.0f + expf(-x));
}

// ---- K1: chunked input GEMM: gates = X_chunk @ Wih^T + bih (fwd chunk cF, bwd chunk cB) ----
__global__ __launch_bounds__(256) void gx_gemm_chunk(
    const float* __restrict__ X,
    const float* __restrict__ Wf, const float* __restrict__ Wb,
    const float* __restrict__ bf, const float* __restrict__ bb,
    float* __restrict__ bufF, float* __restrict__ bufB, int cF, int cB)
{
  __shared__ float As[16][132];
  __shared__ float Bs[16][132];
  const int tid = threadIdx.x;
  const int m0  = blockIdx.x * 128;   // row in [0, MCH)
  int yy = blockIdx.y;
  const float* W; const float* bias; float* buf; int c;
  if (yy < 3) { W = Wf; bias = bf; buf = bufF; c = cF; }
  else        { yy -= 3; W = Wb; bias = bb; buf = bufB; c = cB; }
  const int n0 = yy * 128;

  const int lk = tid & 15;
  const int lr = tid >> 4;
  const int tr = tid >> 4;
  const int tc = tid & 15;

  float acc[8][8];
#pragma unroll
  for (int i = 0; i < 8; i++)
#pragma unroll
    for (int j = 0; j < 8; j++) acc[i][j] = 0.0f;

  for (int kt = 0; kt < DIN; kt += 16) {
#pragma unroll
    for (int i = 0; i < 8; i++) {
      int ml = lr + i * 16;
      int r  = m0 + ml;
      int bb_ = r >> 5;
      int tt  = r & 31;
      int xrow = bb_ * SEQL + c * TCH + tt;
      As[lk][ml] = X[(size_t)xrow * DIN + kt + lk];
    }
#pragma unroll
    for (int i = 0; i < 8; i++) {
      int nl = lr + i * 16;
      Bs[lk][nl] = W[(size_t)(n0 + nl) * DIN + kt + lk];
    }
    __syncthreads();
#pragma unroll
    for (int kk = 0; kk < 16; kk++) {
      float4 a0 = *(const float4*)&As[kk][tr * 8];
      float4 a1 = *(const float4*)&As[kk][tr * 8 + 4];
      float4 b0 = *(const float4*)&Bs[kk][tc * 8];
      float4 b1 = *(const float4*)&Bs[kk][tc * 8 + 4];
      float a[8] = {a0.x,a0.y,a0.z,a0.w,a1.x,a1.y,a1.z,a1.w};
      float bv[8] = {b0.x,b0.y,b0.z,b0.w,b1.x,b1.y,b1.z,b1.w};
#pragma unroll
      for (int i = 0; i < 8; i++)
#pragma unroll
        for (int j = 0; j < 8; j++) acc[i][j] += a[i] * bv[j];
    }
    __syncthreads();
  }

  float bl[8];
#pragma unroll
  for (int j = 0; j < 8; j++) bl[j] = bias[n0 + tc * 8 + j];
#pragma unroll
  for (int i = 0; i < 8; i++) {
    int r = m0 + tr * 8 + i;
    float* row = buf + (size_t)r * G3 + n0 + tc * 8;
    float4 o0, o1;
    o0.x = acc[i][0] + bl[0]; o0.y = acc[i][1] + bl[1];
    o0.z = acc[i][2] + bl[2]; o0.w = acc[i][3] + bl[3];
    o1.x = acc[i][4] + bl[4]; o1.y = acc[i][5] + bl[5];
    o1.z = acc[i][6] + bl[6]; o1.w = acc[i][7] + bl[7];
    *(float4*)&row[0] = o0;
    *(float4*)&row[4] = o1;
  }
}

// ---- K2: batch-grouped GRU scan. 256 blocks = 2 dirs x 128 groups of NB=4 batches. ----
// 384 threads = one gate row each; Whh row held in 128 VGPRs; h in LDS [k][nb].
__global__ __launch_bounds__(384) void gru_scan_chunk(
    const int* __restrict__ seqlens,
    const float* __restrict__ Whh_f, const float* __restrict__ Whh_b,
    const float* __restrict__ bhh_f, const float* __restrict__ bhh_b,
    const float* __restrict__ bufF, const float* __restrict__ bufB,
    float* __restrict__ hstate, __hip_bfloat16* __restrict__ rnn, int ci)
{
  const int fwd = (blockIdx.x < NGRP) ? 1 : 0;
  const int grp = fwd ? blockIdx.x : (blockIdx.x - NGRP);
  const int b0  = grp * NB;
  const int tid = threadIdx.x;
  const float* Whh = fwd ? Whh_f : Whh_b;
  const float* bhh = fwd ? bhh_f : bhh_b;
  const float* buf = fwd ? bufF : bufB;
  const int c = fwd ? ci : (NCH - 1 - ci);

  __shared__ float hs[HID * NB];       // [k][nb] for broadcast b128 reads
  __shared__ float ghs[G3 * 5];        // stride-5 pad: conflict-free
  __shared__ float gxn_l[HID * 5];     // xn passthrough, stride-5 pad

  int len[NB];
#pragma unroll
  for (int nb = 0; nb < NB; nb++) len[nb] = seqlens[b0 + nb];
  int gmax = max(max(len[0], len[1]), max(len[2], len[3]));

  // Whh row -> 128 VGPRs (L2-hot broadcast, amortized over 32 steps)
  const float* wrow = Whh + (size_t)tid * HID;
  float4 wv[32];
#pragma unroll
  for (int i = 0; i < 32; i++) wv[i] = *(const float4*)(wrow + i * 4);
  const float bias = bhh[tid];

  float* hst = hstate + ((size_t)(fwd ? 0 : 1) * NGRP + grp) * (HID * NB);
  float hcur[NB];
  if (tid < HID) {
#pragma unroll
    for (int nb = 0; nb < NB; nb++)
      hcur[nb] = (ci == 0) ? 0.0f : hst[tid * NB + nb];
    float4 h4; h4.x = hcur[0]; h4.y = hcur[1]; h4.z = hcur[2]; h4.w = hcur[3];
    *(float4*)&hs[tid * NB] = h4;
  }
  __syncthreads();

  int nsteps = gmax - c * TCH;
  if (nsteps > TCH) nsteps = TCH;

  for (int ss = 0; ss < nsteps; ++ss) {
    const int tt = fwd ? ss : (nsteps - 1 - ss);
    const int t  = c * TCH + tt;

    // prefetch gx for this step (consumed after the dot phase)
    float gxv[NB];
#pragma unroll
    for (int nb = 0; nb < NB; nb++)
      gxv[nb] = buf[(size_t)((b0 + nb) * TCH + tt) * G3 + tid];

    // 4 independent dot chains, one broadcast b128 per k
    float a0 = 0.f, a1 = 0.f, a2 = 0.f, a3 = 0.f;
#pragma unroll
    for (int k = 0; k < HID; k++) {
      float4 hv = *(const float4*)&hs[k * NB];
      float wk = ((const float*)wv)[k];
      a0 = fmaf(wk, hv.x, a0);
      a1 = fmaf(wk, hv.y, a1);
      a2 = fmaf(wk, hv.z, a2);
      a3 = fmaf(wk, hv.w, a3);
    }
    a0 += bias; a1 += bias; a2 += bias; a3 += bias;

    if (tid < 2 * HID) {   // r,z rows: fold gx in
      ghs[tid * 5 + 0] = a0 + gxv[0];
      ghs[tid * 5 + 1] = a1 + gxv[1];
      ghs[tid * 5 + 2] = a2 + gxv[2];
      ghs[tid * 5 + 3] = a3 + gxv[3];
    } else {               // n rows: keep hn and xn separate (tanh(xn + r*hn))
      ghs[tid * 5 + 0] = a0;
      ghs[tid * 5 + 1] = a1;
      ghs[tid * 5 + 2] = a2;
      ghs[tid * 5 + 3] = a3;
      int rr = tid - 2 * HID;
      gxn_l[rr * 5 + 0] = gxv[0];
      gxn_l[rr * 5 + 1] = gxv[1];
      gxn_l[rr * 5 + 2] = gxv[2];
      gxn_l[rr * 5 + 3] = gxv[3];
    }
    __syncthreads();

    if (tid < HID) {
      float hnew4[NB];
#pragma unroll
      for (int nb = 0; nb < NB; nb++) {
        float gr = ghs[tid * 5 + nb];
        float gz = ghs[(tid + HID) * 5 + nb];
        float hn = ghs[(tid + 2 * HID) * 5 + nb];
        float xn = gxn_l[tid * 5 + nb];
        float r = sigmoidf_(gr);
        float z = sigmoidf_(gz);
        float cand = tanhf(xn + r * hn);
        float hv = (1.0f - z) * cand + z * hcur[nb];
        bool act = (t < len[nb]);
        hv = act ? hv : hcur[nb];
        hcur[nb] = hv;
        hnew4[nb] = hv;
        if (act)
          rnn[(size_t)((b0 + nb) * SEQL + t) * OUTD + (fwd ? 0 : HID) + tid] =
              __float2bfloat16(hv);
      }
      float4 h4; h4.x = hnew4[0]; h4.y = hnew4[1]; h4.z = hnew4[2]; h4.w = hnew4[3];
      *(float4*)&hs[tid * NB] = h4;
    }
    __syncthreads();
  }

  if (tid < HID) {
#pragma unroll
    for (int nb = 0; nb < NB; nb++) hst[tid * NB + nb] = hcur[nb];
  }
}

// ---- K3: scores = ctx . tanh(rnn @ Wmlp^T + bmlp), rnn in bf16 ----
__global__ __launch_bounds__(256) void mlp_score(
    const __hip_bfloat16* __restrict__ rnn,
    const float* __restrict__ Wmlp, const float* __restrict__ bmlp,
    const float* __restrict__ ctx,
    float* __restrict__ scores)
{
  __shared__ float As[16][68];
  __shared__ float Bs[16][260];
  const int tid = threadIdx.x;
  const int m0 = blockIdx.x * 64;
  const int lk = tid & 15;
  const int lr = tid >> 4;
  const int tr = tid >> 5;
  const int tc = tid & 31;

  float acc[8][8];
#pragma unroll
  for (int i = 0; i < 8; i++)
#pragma unroll
    for (int j = 0; j < 8; j++) acc[i][j] = 0.0f;

  for (int kt = 0; kt < OUTD; kt += 16) {
#pragma unroll
    for (int i = 0; i < 4; i++) {
      int ml = lr + i * 16;
      As[lk][ml] = __bfloat162float(rnn[(size_t)(m0 + ml) * OUTD + kt + lk]);
    }
#pragma unroll
    for (int i = 0; i < 16; i++) {
      int nl = lr + i * 16;
      Bs[lk][nl] = Wmlp[(size_t)nl * OUTD + kt + lk];
    }
    __syncthreads();
#pragma unroll
    for (int kk = 0; kk < 16; kk++) {
      float4 a0 = *(const float4*)&As[kk][tr * 8];
      float4 a1 = *(const float4*)&As[kk][tr * 8 + 4];
      float4 b0 = *(const float4*)&Bs[kk][tc * 8];
      float4 b1 = *(const float4*)&Bs[kk][tc * 8 + 4];
      float a[8] = {a0.x,a0.y,a0.z,a0.w,a1.x,a1.y,a1.z,a1.w};
      float bv[8] = {b0.x,b0.y,b0.z,b0.w,b1.x,b1.y,b1.z,b1.w};
#pragma unroll
      for (int i = 0; i < 8; i++)
#pragma unroll
        for (int j = 0; j < 8; j++) acc[i][j] += a[i] * bv[j];
    }
    __syncthreads();
  }

  float bl[8], cl[8];
#pragma unroll
  for (int j = 0; j < 8; j++) { bl[j] = bmlp[tc * 8 + j]; cl[j] = ctx[tc * 8 + j]; }

  float part[8];
#pragma unroll
  for (int i = 0; i < 8; i++) {
    float p = 0.0f;
#pragma unroll
    for (int j = 0; j < 8; j++) p += tanhf(acc[i][j] + bl[j]) * cl[j];
    part[i] = p;
  }
#pragma unroll
  for (int off = 16; off > 0; off >>= 1)
#pragma unroll
    for (int i = 0; i < 8; i++) part[i] += __shfl_xor(part[i], off, 64);

  if (tc == 0) {
#pragma unroll
    for (int i = 0; i < 8; i++) scores[m0 + tr * 8 + i] = part[i];
  }
}

// ---- K4: masked softmax over l + weighted pool (rnn bf16 -> out fp32) ----
__global__ __launch_bounds__(256) void softmax_pool(
    const int* __restrict__ seqlens,
    const float* __restrict__ scores,
    const __hip_bfloat16* __restrict__ rnn,
    float* __restrict__ out)
{
  const int b = blockIdx.x;
  const int len = seqlens[b];
  const int tid = threadIdx.x;
  __shared__ float sm[SEQL];
  __shared__ float red[8];

  float s = (tid < len) ? scores[b * SEQL + tid] : -3.4e38f;
  float wm = s;
#pragma unroll
  for (int off = 32; off > 0; off >>= 1) wm = fmaxf(wm, __shfl_xor(wm, off, 64));
  if ((tid & 63) == 0) red[tid >> 6] = wm;
  __syncthreads();
  float bm = fmaxf(fmaxf(red[0], red[1]), fmaxf(red[2], red[3]));

  float e = (tid < len) ? expf(s - bm) : 0.0f;
  sm[tid] = e;
  float sum = e;
#pragma unroll
  for (int off = 32; off > 0; off >>= 1) sum += __shfl_xor(sum, off, 64);
  if ((tid & 63) == 0) red[4 + (tid >> 6)] = sum;
  __syncthreads();
  float inv = 1.0f / (red[4] + red[5] + red[6] + red[7]);

  float acc = 0.0f;
  for (int l = 0; l < len; ++l)
    acc += sm[l] * __bfloat162float(rnn[(size_t)(b * SEQL + l) * OUTD + tid]);
  out[b * OUTD + tid] = acc * inv;
}

extern "C" void kernel_launch(void* const* d_in, const int* in_sizes, int n_in,
                              void* d_out, int out_size, void* d_ws, size_t ws_size,
                              hipStream_t stream) {
  const float* seq    = (const float*)d_in[0];
  const int*   lens   = (const int*)d_in[1];
  const float* Wih_f  = (const float*)d_in[2];
  const float* Whh_f  = (const float*)d_in[3];
  const float* bih_f  = (const float*)d_in[4];
  const float* bhh_f  = (const float*)d_in[5];
  const float* Wih_b  = (const float*)d_in[6];
  const float* Whh_b  = (const float*)d_in[7];
  const float* bih_b  = (const float*)d_in[8];
  const float* bhh_b  = (const float*)d_in[9];
  const float* Wmlp   = (const float*)d_in[10];
  const float* bmlp   = (const float*)d_in[11];
  const float* ctx    = (const float*)d_in[12];
  float* out = (float*)d_out;

  // ws layout: bufF 25.2MB | bufB 25.2MB | rnn bf16 67.1MB | scores 0.5MB | hstate 1MB
  float* bufF = (float*)d_ws;
  float* bufB = bufF + (size_t)MCH * G3;
  __hip_bfloat16* rnn = (__hip_bfloat16*)(bufB + (size_t)MCH * G3);
  float* scores = (float*)(rnn + (size_t)MTOT * OUTD);
  float* hstate = scores + MTOT;

  dim3 gG(MCH / 128, 6);
  for (int ci = 0; ci < NCH; ++ci) {
    gx_gemm_chunk<<<gG, 256, 0, stream>>>(seq, Wih_f, Wih_b, bih_f, bih_b,
                                          bufF, bufB, ci, NCH - 1 - ci);
    gru_scan_chunk<<<dim3(2 * NGRP), 384, 0, stream>>>(
        lens, Whh_f, Whh_b, bhh_f, bhh_b, bufF, bufB, hstate, rnn, ci);
  }
  mlp_score<<<dim3(MTOT / 64), 256, 0, stream>>>(rnn, Wmlp, bmlp, ctx, scores);
  softmax_pool<<<dim3(BATCH), 256, 0, stream>>>(lens, scores, rnn, out);
}

// Round 4
// 2165.437 us; speedup vs baseline: 2.7908x; 1.1726x over previous
//
#include <hip/hip_runtime.h>
#include <hip/hip_bf16.h>
#include <cstdint>
#include <cstddef>

#define BATCH 512
#define SEQL 256
#define DIN 256
#define HID 128
#define OUTD 256
#define G3 384            // 3*H
#define TCH 32            // time chunk
#define NCH 8             // SEQL / TCH
#define NB 4              // batches per scan block
#define NGRP (BATCH/NB)   // 128 groups per dir
#define MTOT (BATCH*SEQL) // 131072
#define MCH  (BATCH*TCH)  // 16384 rows per chunk per dir

typedef __attribute__((ext_vector_type(8))) short short8v;
typedef __attribute__((ext_vector_type(4))) float float4v;

__device__ __forceinline__ float sigmoidf_(float x) {
  return 1.0f / (1.0f + expf(-x));
}
__device__ __forceinline__ unsigned short f2bf_u(float x) {
  union { float f; uint32_t u; } v; v.f = x;
  uint32_t r = v.u + 0x7FFFu + ((v.u >> 16) & 1u);
  return (unsigned short)(r >> 16);
}
__device__ __forceinline__ float bfu2f(unsigned short u) {
  union { uint32_t u; float f; } v; v.u = ((uint32_t)u) << 16; return v.f;
}

// ---- K1: chunked input GEMM via MFMA, 3-term bf16 split (fp32-class accuracy) ----
// grid (128, 12): x = M-tile (128 rows of 16384), y<6 fwd N-tile (64 gates), y>=6 bwd.
__global__ __launch_bounds__(256) void gx_gemm_chunk(
    const float* __restrict__ X,
    const float* __restrict__ Wf, const float* __restrict__ Wb,
    const float* __restrict__ bf, const float* __restrict__ bb,
    float* __restrict__ bufF, float* __restrict__ bufB, int cF, int cB)
{
  __shared__ unsigned short Ahi[128 * 40];
  __shared__ unsigned short Alo[128 * 40];
  __shared__ unsigned short Bhi[64 * 40];
  __shared__ unsigned short Blo[64 * 40];

  const int tid = threadIdx.x;
  const int m0  = blockIdx.x * 128;
  int yy = blockIdx.y;
  const float* W; const float* bias; float* buf; int c;
  if (yy < 6) { W = Wf; bias = bf; buf = bufF; c = cF; }
  else        { yy -= 6; W = Wb; bias = bb; buf = bufB; c = cB; }
  const int n0 = yy * 64;

  const int l  = tid & 63;
  const int w  = tid >> 6;
  const int fr = l & 15;
  const int fk = (l >> 4) * 8;

  float4v acc[2][4];
#pragma unroll
  for (int a = 0; a < 2; ++a)
#pragma unroll
    for (int nb = 0; nb < 4; ++nb) acc[a][nb] = (float4v)0.0f;

  for (int k0 = 0; k0 < DIN; k0 += 32) {
    // stage A: 128 rows x 32 k, fp32 -> hi/lo bf16
#pragma unroll
    for (int j = 0; j < 4; ++j) {
      int row = (tid >> 3) + j * 32;
      int kq  = (tid & 7) * 4;
      int r   = m0 + row;
      int b_  = r >> 5, tt = r & 31;
      int xrow = b_ * SEQL + c * TCH + tt;
      float4 x4 = *(const float4*)&X[(size_t)xrow * DIN + k0 + kq];
      unsigned short h0 = f2bf_u(x4.x), h1 = f2bf_u(x4.y), h2 = f2bf_u(x4.z), h3 = f2bf_u(x4.w);
      ushort4 hi4 = {h0, h1, h2, h3};
      ushort4 lo4 = {f2bf_u(x4.x - bfu2f(h0)), f2bf_u(x4.y - bfu2f(h1)),
                     f2bf_u(x4.z - bfu2f(h2)), f2bf_u(x4.w - bfu2f(h3))};
      *(ushort4*)&Ahi[row * 40 + kq] = hi4;
      *(ushort4*)&Alo[row * 40 + kq] = lo4;
    }
    // stage B: 64 gate rows x 32 k
#pragma unroll
    for (int j = 0; j < 2; ++j) {
      int col = (tid >> 3) + j * 32;
      int kq  = (tid & 7) * 4;
      float4 w4 = *(const float4*)&W[(size_t)(n0 + col) * DIN + k0 + kq];
      unsigned short h0 = f2bf_u(w4.x), h1 = f2bf_u(w4.y), h2 = f2bf_u(w4.z), h3 = f2bf_u(w4.w);
      ushort4 hi4 = {h0, h1, h2, h3};
      ushort4 lo4 = {f2bf_u(w4.x - bfu2f(h0)), f2bf_u(w4.y - bfu2f(h1)),
                     f2bf_u(w4.z - bfu2f(h2)), f2bf_u(w4.w - bfu2f(h3))};
      *(ushort4*)&Bhi[col * 40 + kq] = hi4;
      *(ushort4*)&Blo[col * 40 + kq] = lo4;
    }
    __syncthreads();

    short8v ah[2], al[2], bh[4], blv[4];
#pragma unroll
    for (int a = 0; a < 2; ++a) {
      ah[a] = *(const short8v*)&Ahi[(w * 32 + a * 16 + fr) * 40 + fk];
      al[a] = *(const short8v*)&Alo[(w * 32 + a * 16 + fr) * 40 + fk];
    }
#pragma unroll
    for (int nb = 0; nb < 4; ++nb) {
      bh[nb]  = *(const short8v*)&Bhi[(nb * 16 + fr) * 40 + fk];
      blv[nb] = *(const short8v*)&Blo[(nb * 16 + fr) * 40 + fk];
    }
#pragma unroll
    for (int a = 0; a < 2; ++a)
#pragma unroll
      for (int nb = 0; nb < 4; ++nb) {
        acc[a][nb] = __builtin_amdgcn_mfma_f32_16x16x32_bf16(ah[a], bh[nb],  acc[a][nb], 0, 0, 0);
        acc[a][nb] = __builtin_amdgcn_mfma_f32_16x16x32_bf16(ah[a], blv[nb], acc[a][nb], 0, 0, 0);
        acc[a][nb] = __builtin_amdgcn_mfma_f32_16x16x32_bf16(al[a], bh[nb],  acc[a][nb], 0, 0, 0);
      }
    __syncthreads();
  }

  // epilogue: add bias, write fp32 buf
#pragma unroll
  for (int a = 0; a < 2; ++a)
#pragma unroll
    for (int nb = 0; nb < 4; ++nb) {
      int gate = n0 + nb * 16 + fr;
      float bv_ = bias[gate];
#pragma unroll
      for (int reg = 0; reg < 4; ++reg) {
        int r = m0 + w * 32 + a * 16 + (l >> 4) * 4 + reg;
        buf[(size_t)r * G3 + gate] = acc[a][nb][reg] + bv_;
      }
    }
}

// ---- K2: batch-grouped GRU scan, depth-2 pipelined dot ----
__global__ __launch_bounds__(384) void gru_scan_chunk(
    const int* __restrict__ seqlens,
    const float* __restrict__ Whh_f, const float* __restrict__ Whh_b,
    const float* __restrict__ bhh_f, const float* __restrict__ bhh_b,
    const float* __restrict__ bufF, const float* __restrict__ bufB,
    float* __restrict__ hstate, __hip_bfloat16* __restrict__ rnn, int ci)
{
  const int fwd = (blockIdx.x < NGRP) ? 1 : 0;
  const int grp = fwd ? blockIdx.x : (blockIdx.x - NGRP);
  const int b0  = grp * NB;
  const int tid = threadIdx.x;
  const float* Whh = fwd ? Whh_f : Whh_b;
  const float* bhh = fwd ? bhh_f : bhh_b;
  const float* buf = fwd ? bufF : bufB;
  const int c = fwd ? ci : (NCH - 1 - ci);

  __shared__ float hs[HID * NB];       // [k][nb]
  __shared__ float ghs[G3 * 5];        // stride-5 pad
  __shared__ float gxn_l[HID * 5];

  int len[NB];
#pragma unroll
  for (int nb = 0; nb < NB; nb++) len[nb] = seqlens[b0 + nb];
  int gmax = max(max(len[0], len[1]), max(len[2], len[3]));

  const float* wrow = Whh + (size_t)tid * HID;
  float4 wv[32];
#pragma unroll
  for (int i = 0; i < 32; i++) wv[i] = *(const float4*)(wrow + i * 4);
  const float bias = bhh[tid];
  const float* wf = (const float*)wv;

  float* hst = hstate + ((size_t)(fwd ? 0 : 1) * NGRP + grp) * (HID * NB);
  float hcur[NB];
  if (tid < HID) {
#pragma unroll
    for (int nb = 0; nb < NB; nb++)
      hcur[nb] = (ci == 0) ? 0.0f : hst[tid * NB + nb];
    float4 h4; h4.x = hcur[0]; h4.y = hcur[1]; h4.z = hcur[2]; h4.w = hcur[3];
    *(float4*)&hs[tid * NB] = h4;
  }
  __syncthreads();

  int nsteps = gmax - c * TCH;
  if (nsteps > TCH) nsteps = TCH;

  for (int ss = 0; ss < nsteps; ++ss) {
    const int tt = fwd ? ss : (nsteps - 1 - ss);
    const int t  = c * TCH + tt;

    float gxv[NB];
#pragma unroll
    for (int nb = 0; nb < NB; nb++)
      gxv[nb] = buf[(size_t)((b0 + nb) * TCH + tt) * G3 + tid];

    // depth-2 pipelined dot: groups of 8 k (8 x ds_read_b128), 3 buffers
    float a0 = 0.f, a1 = 0.f, a2 = 0.f, a3 = 0.f;
    float4 bA[8], bB[8], bC[8];
#pragma unroll
    for (int i = 0; i < 8; ++i) bA[i] = *(const float4*)&hs[(0 * 8 + i) * NB];
#pragma unroll
    for (int i = 0; i < 8; ++i) bB[i] = *(const float4*)&hs[(1 * 8 + i) * NB];
#pragma unroll
    for (int g = 0; g < 16; ++g) {
      const float4* cur = (g % 3 == 0) ? bA : (g % 3 == 1) ? bB : bC;
      if (g < 14) {
        float4* pre = ((g + 2) % 3 == 0) ? bA : ((g + 2) % 3 == 1) ? bB : bC;
#pragma unroll
        for (int i = 0; i < 8; ++i)
          pre[i] = *(const float4*)&hs[((g + 2) * 8 + i) * NB];
      }
#pragma unroll
      for (int i = 0; i < 8; ++i) {
        float wk = wf[g * 8 + i];
        float4 hv = cur[i];
        a0 = fmaf(wk, hv.x, a0);
        a1 = fmaf(wk, hv.y, a1);
        a2 = fmaf(wk, hv.z, a2);
        a3 = fmaf(wk, hv.w, a3);
      }
    }
    a0 += bias; a1 += bias; a2 += bias; a3 += bias;

    if (tid < 2 * HID) {
      ghs[tid * 5 + 0] = a0 + gxv[0];
      ghs[tid * 5 + 1] = a1 + gxv[1];
      ghs[tid * 5 + 2] = a2 + gxv[2];
      ghs[tid * 5 + 3] = a3 + gxv[3];
    } else {
      ghs[tid * 5 + 0] = a0;
      ghs[tid * 5 + 1] = a1;
      ghs[tid * 5 + 2] = a2;
      ghs[tid * 5 + 3] = a3;
      int rr = tid - 2 * HID;
      gxn_l[rr * 5 + 0] = gxv[0];
      gxn_l[rr * 5 + 1] = gxv[1];
      gxn_l[rr * 5 + 2] = gxv[2];
      gxn_l[rr * 5 + 3] = gxv[3];
    }
    __syncthreads();

    if (tid < HID) {
      float hnew4[NB];
#pragma unroll
      for (int nb = 0; nb < NB; nb++) {
        float gr = ghs[tid * 5 + nb];
        float gz = ghs[(tid + HID) * 5 + nb];
        float hn = ghs[(tid + 2 * HID) * 5 + nb];
        float xn = gxn_l[tid * 5 + nb];
        float r = sigmoidf_(gr);
        float z = sigmoidf_(gz);
        float cand = tanhf(xn + r * hn);
        float hv = (1.0f - z) * cand + z * hcur[nb];
        bool act = (t < len[nb]);
        hv = act ? hv : hcur[nb];
        hcur[nb] = hv;
        hnew4[nb] = hv;
        if (act)
          rnn[(size_t)((b0 + nb) * SEQL + t) * OUTD + (fwd ? 0 : HID) + tid] =
              __float2bfloat16(hv);
      }
      float4 h4; h4.x = hnew4[0]; h4.y = hnew4[1]; h4.z = hnew4[2]; h4.w = hnew4[3];
      *(float4*)&hs[tid * NB] = h4;
    }
    __syncthreads();
  }

  if (tid < HID) {
#pragma unroll
    for (int nb = 0; nb < NB; nb++) hst[tid * NB + nb] = hcur[nb];
  }
}

// ---- K3: scores via MFMA: A = rnn bf16, B = Wmlp hi/lo split; fused tanh+ctx epilogue ----
// grid 2048: block = 64 rows x 256 cols, 4 waves, wave w -> rows w*16..+16.
__global__ __launch_bounds__(256) void mlp_score(
    const __hip_bfloat16* __restrict__ rnn,
    const float* __restrict__ Wmlp, const float* __restrict__ bmlp,
    const float* __restrict__ ctx,
    float* __restrict__ scores)
{
  __shared__ unsigned short Abf[64 * 40];
  __shared__ unsigned short Bhi[256 * 40];
  __shared__ unsigned short Blo[256 * 40];

  const int tid = threadIdx.x;
  const int m0  = blockIdx.x * 64;
  const int l   = tid & 63;
  const int w   = tid >> 6;
  const int fr  = l & 15;
  const int fk  = (l >> 4) * 8;

  float bl_[16], cl_[16];
#pragma unroll
  for (int nt = 0; nt < 16; ++nt) {
    bl_[nt] = bmlp[nt * 16 + fr];
    cl_[nt] = ctx[nt * 16 + fr];
  }

  float4v acc[16];
#pragma unroll
  for (int nt = 0; nt < 16; ++nt) acc[nt] = (float4v)0.0f;

  for (int k0 = 0; k0 < OUTD; k0 += 32) {
    // stage A (bf16 direct): 64 rows x 32 k
    {
      int row = tid >> 2;
      int kq  = (tid & 3) * 8;
      *(short8v*)&Abf[row * 40 + kq] =
          *(const short8v*)((const short*)rnn + (size_t)(m0 + row) * OUTD + k0 + kq);
    }
    // stage B: 256 cols x 32 k, fp32 -> hi/lo
#pragma unroll
    for (int j = 0; j < 8; ++j) {
      int col = (tid >> 3) + j * 32;
      int kq  = (tid & 7) * 4;
      float4 w4 = *(const float4*)&Wmlp[(size_t)col * OUTD + k0 + kq];
      unsigned short h0 = f2bf_u(w4.x), h1 = f2bf_u(w4.y), h2 = f2bf_u(w4.z), h3 = f2bf_u(w4.w);
      ushort4 hi4 = {h0, h1, h2, h3};
      ushort4 lo4 = {f2bf_u(w4.x - bfu2f(h0)), f2bf_u(w4.y - bfu2f(h1)),
                     f2bf_u(w4.z - bfu2f(h2)), f2bf_u(w4.w - bfu2f(h3))};
      *(ushort4*)&Bhi[col * 40 + kq] = hi4;
      *(ushort4*)&Blo[col * 40 + kq] = lo4;
    }
    __syncthreads();

    short8v a = *(const short8v*)&Abf[(w * 16 + fr) * 40 + fk];
#pragma unroll
    for (int nt = 0; nt < 16; ++nt) {
      short8v bh = *(const short8v*)&Bhi[(nt * 16 + fr) * 40 + fk];
      short8v bl = *(const short8v*)&Blo[(nt * 16 + fr) * 40 + fk];
      acc[nt] = __builtin_amdgcn_mfma_f32_16x16x32_bf16(a, bh, acc[nt], 0, 0, 0);
      acc[nt] = __builtin_amdgcn_mfma_f32_16x16x32_bf16(a, bl, acc[nt], 0, 0, 0);
    }
    __syncthreads();
  }

  // epilogue: tanh + ctx dot + 16-lane reduce
  float p[4] = {0.f, 0.f, 0.f, 0.f};
#pragma unroll
  for (int nt = 0; nt < 16; ++nt) {
    float bv_ = bl_[nt], cv = cl_[nt];
#pragma unroll
    for (int reg = 0; reg < 4; ++reg)
      p[reg] += tanhf(acc[nt][reg] + bv_) * cv;
  }
#pragma unroll
  for (int off = 1; off < 16; off <<= 1)
#pragma unroll
    for (int reg = 0; reg < 4; ++reg) p[reg] += __shfl_xor(p[reg], off, 64);

  if (fr == 0) {
#pragma unroll
    for (int reg = 0; reg < 4; ++reg)
      scores[m0 + w * 16 + (l >> 4) * 4 + reg] = p[reg];
  }
}

// ---- K4: masked softmax over l + weighted pool ----
__global__ __launch_bounds__(256) void softmax_pool(
    const int* __restrict__ seqlens,
    const float* __restrict__ scores,
    const __hip_bfloat16* __restrict__ rnn,
    float* __restrict__ out)
{
  const int b = blockIdx.x;
  const int len = seqlens[b];
  const int tid = threadIdx.x;
  __shared__ float sm[SEQL];
  __shared__ float red[8];

  float s = (tid < len) ? scores[b * SEQL + tid] : -3.4e38f;
  float wm = s;
#pragma unroll
  for (int off = 32; off > 0; off >>= 1) wm = fmaxf(wm, __shfl_xor(wm, off, 64));
  if ((tid & 63) == 0) red[tid >> 6] = wm;
  __syncthreads();
  float bm = fmaxf(fmaxf(red[0], red[1]), fmaxf(red[2], red[3]));

  float e = (tid < len) ? expf(s - bm) : 0.0f;
  sm[tid] = e;
  float sum = e;
#pragma unroll
  for (int off = 32; off > 0; off >>= 1) sum += __shfl_xor(sum, off, 64);
  if ((tid & 63) == 0) red[4 + (tid >> 6)] = sum;
  __syncthreads();
  float inv = 1.0f / (red[4] + red[5] + red[6] + red[7]);

  float acc = 0.0f;
  for (int l = 0; l < len; ++l)
    acc += sm[l] * __bfloat162float(rnn[(size_t)(b * SEQL + l) * OUTD + tid]);
  out[b * OUTD + tid] = acc * inv;
}

extern "C" void kernel_launch(void* const* d_in, const int* in_sizes, int n_in,
                              void* d_out, int out_size, void* d_ws, size_t ws_size,
                              hipStream_t stream) {
  const float* seq    = (const float*)d_in[0];
  const int*   lens   = (const int*)d_in[1];
  const float* Wih_f  = (const float*)d_in[2];
  const float* Whh_f  = (const float*)d_in[3];
  const float* bih_f  = (const float*)d_in[4];
  const float* bhh_f  = (const float*)d_in[5];
  const float* Wih_b  = (const float*)d_in[6];
  const float* Whh_b  = (const float*)d_in[7];
  const float* bih_b  = (const float*)d_in[8];
  const float* bhh_b  = (const float*)d_in[9];
  const float* Wmlp   = (const float*)d_in[10];
  const float* bmlp   = (const float*)d_in[11];
  const float* ctx    = (const float*)d_in[12];
  float* out = (float*)d_out;

  // ws layout: bufF 25.2MB | bufB 25.2MB | rnn bf16 67.1MB | scores 0.5MB | hstate 1MB
  float* bufF = (float*)d_ws;
  float* bufB = bufF + (size_t)MCH * G3;
  __hip_bfloat16* rnn = (__hip_bfloat16*)(bufB + (size_t)MCH * G3);
  float* scores = (float*)(rnn + (size_t)MTOT * OUTD);
  float* hstate = scores + MTOT;

  dim3 gG(MCH / 128, 12);
  for (int ci = 0; ci < NCH; ++ci) {
    gx_gemm_chunk<<<gG, 256, 0, stream>>>(seq, Wih_f, Wih_b, bih_f, bih_b,
                                          bufF, bufB, ci, NCH - 1 - ci);
    gru_scan_chunk<<<dim3(2 * NGRP), 384, 0, stream>>>(
        lens, Whh_f, Whh_b, bhh_f, bhh_b, bufF, bufB, hstate, rnn, ci);
  }
  mlp_score<<<dim3(MTOT / 64), 256, 0, stream>>>(rnn, Wmlp, bmlp, ctx, scores);
  softmax_pool<<<dim3(BATCH), 256, 0, stream>>>(lens, scores, rnn, out);
}

// Round 5
// 972.498 us; speedup vs baseline: 6.2143x; 2.2267x over previous
//
#include <hip/hip_runtime.h>
#include <hip/hip_bf16.h>
#include <cstdint>
#include <cstddef>

#define BATCH 512
#define SEQL 256
#define DIN 256
#define HID 128
#define OUTD 256
#define G3 384            // 3*H
#define TCH 32            // time chunk
#define NCH 8             // SEQL / TCH
#define NBS 16            // batches per scan block
#define NGRPS (BATCH/NBS) // 32 groups per dir
#define MTOT (BATCH*SEQL) // 131072
#define MCH  (BATCH*TCH)  // 16384 rows per chunk per dir
#define HSPAD 136         // hs row pad (ushorts): 16B-aligned rows, even bank spread

typedef __attribute__((ext_vector_type(8))) short short8v;
typedef __attribute__((ext_vector_type(4))) float float4v;

__device__ __forceinline__ unsigned short f2bf_u(float x) {
  union { float f; uint32_t u; } v; v.f = x;
  uint32_t r = v.u + 0x7FFFu + ((v.u >> 16) & 1u);
  return (unsigned short)(r >> 16);
}
__device__ __forceinline__ float bfu2f(unsigned short u) {
  union { uint32_t u; float f; } v; v.u = ((uint32_t)u) << 16; return v.f;
}

// ---- K1: chunked input GEMM via MFMA, 3-term bf16 split (fp32-class accuracy) ----
__global__ __launch_bounds__(256) void gx_gemm_chunk(
    const float* __restrict__ X,
    const float* __restrict__ Wf, const float* __restrict__ Wb,
    const float* __restrict__ bf, const float* __restrict__ bb,
    float* __restrict__ bufF, float* __restrict__ bufB, int cF, int cB)
{
  __shared__ unsigned short Ahi[128 * 40];
  __shared__ unsigned short Alo[128 * 40];
  __shared__ unsigned short Bhi[64 * 40];
  __shared__ unsigned short Blo[64 * 40];

  const int tid = threadIdx.x;
  const int m0  = blockIdx.x * 128;
  int yy = blockIdx.y;
  const float* W; const float* bias; float* buf; int c;
  if (yy < 6) { W = Wf; bias = bf; buf = bufF; c = cF; }
  else        { yy -= 6; W = Wb; bias = bb; buf = bufB; c = cB; }
  const int n0 = yy * 64;

  const int l  = tid & 63;
  const int w  = tid >> 6;
  const int fr = l & 15;
  const int fk = (l >> 4) * 8;

  float4v acc[2][4];
#pragma unroll
  for (int a = 0; a < 2; ++a)
#pragma unroll
    for (int nb = 0; nb < 4; ++nb) acc[a][nb] = (float4v)0.0f;

  for (int k0 = 0; k0 < DIN; k0 += 32) {
#pragma unroll
    for (int j = 0; j < 4; ++j) {
      int row = (tid >> 3) + j * 32;
      int kq  = (tid & 7) * 4;
      int r   = m0 + row;
      int b_  = r >> 5, tt = r & 31;
      int xrow = b_ * SEQL + c * TCH + tt;
      float4 x4 = *(const float4*)&X[(size_t)xrow * DIN + k0 + kq];
      unsigned short h0 = f2bf_u(x4.x), h1 = f2bf_u(x4.y), h2 = f2bf_u(x4.z), h3 = f2bf_u(x4.w);
      ushort4 hi4 = {h0, h1, h2, h3};
      ushort4 lo4 = {f2bf_u(x4.x - bfu2f(h0)), f2bf_u(x4.y - bfu2f(h1)),
                     f2bf_u(x4.z - bfu2f(h2)), f2bf_u(x4.w - bfu2f(h3))};
      *(ushort4*)&Ahi[row * 40 + kq] = hi4;
      *(ushort4*)&Alo[row * 40 + kq] = lo4;
    }
#pragma unroll
    for (int j = 0; j < 2; ++j) {
      int col = (tid >> 3) + j * 32;
      int kq  = (tid & 7) * 4;
      float4 w4 = *(const float4*)&W[(size_t)(n0 + col) * DIN + k0 + kq];
      unsigned short h0 = f2bf_u(w4.x), h1 = f2bf_u(w4.y), h2 = f2bf_u(w4.z), h3 = f2bf_u(w4.w);
      ushort4 hi4 = {h0, h1, h2, h3};
      ushort4 lo4 = {f2bf_u(w4.x - bfu2f(h0)), f2bf_u(w4.y - bfu2f(h1)),
                     f2bf_u(w4.z - bfu2f(h2)), f2bf_u(w4.w - bfu2f(h3))};
      *(ushort4*)&Bhi[col * 40 + kq] = hi4;
      *(ushort4*)&Blo[col * 40 + kq] = lo4;
    }
    __syncthreads();

    short8v ah[2], al[2], bh[4], blv[4];
#pragma unroll
    for (int a = 0; a < 2; ++a) {
      ah[a] = *(const short8v*)&Ahi[(w * 32 + a * 16 + fr) * 40 + fk];
      al[a] = *(const short8v*)&Alo[(w * 32 + a * 16 + fr) * 40 + fk];
    }
#pragma unroll
    for (int nb = 0; nb < 4; ++nb) {
      bh[nb]  = *(const short8v*)&Bhi[(nb * 16 + fr) * 40 + fk];
      blv[nb] = *(const short8v*)&Blo[(nb * 16 + fr) * 40 + fk];
    }
#pragma unroll
    for (int a = 0; a < 2; ++a)
#pragma unroll
      for (int nb = 0; nb < 4; ++nb) {
        acc[a][nb] = __builtin_amdgcn_mfma_f32_16x16x32_bf16(ah[a], bh[nb],  acc[a][nb], 0, 0, 0);
        acc[a][nb] = __builtin_amdgcn_mfma_f32_16x16x32_bf16(ah[a], blv[nb], acc[a][nb], 0, 0, 0);
        acc[a][nb] = __builtin_amdgcn_mfma_f32_16x16x32_bf16(al[a], bh[nb],  acc[a][nb], 0, 0, 0);
      }
    __syncthreads();
  }

#pragma unroll
  for (int a = 0; a < 2; ++a)
#pragma unroll
    for (int nb = 0; nb < 4; ++nb) {
      int gate = n0 + nb * 16 + fr;
      float bv_ = bias[gate];
#pragma unroll
      for (int reg = 0; reg < 4; ++reg) {
        int r = m0 + w * 32 + a * 16 + (l >> 4) * 4 + reg;
        buf[(size_t)r * G3 + gate] = acc[a][nb][reg] + bv_;
      }
    }
}

// ---- K2: MFMA GRU scan. grid 64 = 2 dirs x 32 groups of 16 batches; 512 thr (8 waves). ----
// Wave w owns hidx [w*16, w*16+16): gate tiles r/z/n at {hidx, 128+hidx, 256+hidx}.
// Whh B-fragments (hi/lo bf16) in 96 VGPRs, loaded once. h: fp32 in owner-lane regs,
// bf16 hi/lo in LDS for the next step's A-fragment.
__global__ __launch_bounds__(512, 2) void gru_scan_mfma(
    const int* __restrict__ seqlens,
    const float* __restrict__ Whh_f, const float* __restrict__ Whh_b,
    const float* __restrict__ bhh_f, const float* __restrict__ bhh_b,
    const float* __restrict__ bufF, const float* __restrict__ bufB,
    float* __restrict__ hstate, __hip_bfloat16* __restrict__ rnn, int ci)
{
  const int fwd = (blockIdx.x < NGRPS) ? 1 : 0;
  const int grp = fwd ? blockIdx.x : (blockIdx.x - NGRPS);
  const int b0  = grp * NBS;
  const int tid = threadIdx.x;
  const int w   = tid >> 6;
  const int l   = tid & 63;
  const int col = l & 15;     // hidx-within-wave-tile AND A-operand batch index
  const int rq  = l >> 4;     // row quad: C rows rq*4..rq*4+4 (batches)
  const int hidx = w * 16 + col;
  const float* Whh = fwd ? Whh_f : Whh_b;
  const float* bhh = fwd ? bhh_f : bhh_b;
  const float* buf = fwd ? bufF : bufB;
  const int c = fwd ? ci : (NCH - 1 - ci);

  __shared__ unsigned short hs_hi[NBS * HSPAD];
  __shared__ unsigned short hs_lo[NBS * HSPAD];

  // ---- one-time: B fragments (3 tiles x 4 ksteps, hi+lo) + biases ----
  short8v Bh[3][4], Bl[3][4];
  float bias_[3];
#pragma unroll
  for (int j = 0; j < 3; ++j) {
    const int g = j * HID + hidx;
    bias_[j] = bhh[g];
#pragma unroll
    for (int ks = 0; ks < 4; ++ks) {
      const float* p = Whh + (size_t)g * HID + ks * 32 + rq * 8;
      float4 x0 = *(const float4*)p;
      float4 x1 = *(const float4*)(p + 4);
      float v[8] = {x0.x, x0.y, x0.z, x0.w, x1.x, x1.y, x1.z, x1.w};
      short8v hi8, lo8;
#pragma unroll
      for (int e = 0; e < 8; ++e) {
        unsigned short h = f2bf_u(v[e]);
        hi8[e] = (short)h;
        lo8[e] = (short)f2bf_u(v[e] - bfu2f(h));
      }
      Bh[j][ks] = hi8; Bl[j][ks] = lo8;
    }
  }

  // ---- lengths ----
  int len_[4];
#pragma unroll
  for (int reg = 0; reg < 4; ++reg) len_[reg] = seqlens[b0 + rq * 4 + reg];
  int gmax = 0;
  for (int nb = 0; nb < NBS; ++nb) gmax = max(gmax, seqlens[b0 + nb]);

  // ---- h init: fp32 regs (owner lane) + LDS hi/lo ----
  float* hst = hstate + ((size_t)((fwd ? 0 : 1) * NGRPS + grp)) * (NBS * HID);
  float hold[4];
#pragma unroll
  for (int reg = 0; reg < 4; ++reg) {
    int nb = rq * 4 + reg;
    hold[reg] = (ci == 0) ? 0.0f : hst[nb * HID + hidx];
    unsigned short hh = f2bf_u(hold[reg]);
    hs_hi[nb * HSPAD + hidx] = hh;
    hs_lo[nb * HSPAD + hidx] = f2bf_u(hold[reg] - bfu2f(hh));
  }
  __syncthreads();

  int nsteps = gmax - c * TCH;
  nsteps = (nsteps > TCH) ? TCH : nsteps;

  // gx register double-buffer; prologue load for ss=0
  float gxc[3][4], gxn[3][4];
  if (nsteps > 0) {
    int tt0 = fwd ? 0 : (nsteps - 1);
#pragma unroll
    for (int j = 0; j < 3; ++j)
#pragma unroll
      for (int reg = 0; reg < 4; ++reg)
        gxc[j][reg] = buf[(size_t)((b0 + rq * 4 + reg) * TCH + tt0) * G3 + j * HID + hidx];
  }

  for (int ss = 0; ss < nsteps; ++ss) {
    const int tt = fwd ? ss : (nsteps - 1 - ss);
    const int t  = c * TCH + tt;

    // A-fragment reads (this step's h)
    short8v ah[4], al[4];
#pragma unroll
    for (int ks = 0; ks < 4; ++ks) {
      ah[ks] = *(const short8v*)&hs_hi[col * HSPAD + ks * 32 + rq * 8];
      al[ks] = *(const short8v*)&hs_lo[col * HSPAD + ks * 32 + rq * 8];
    }
    __syncthreads();   // everyone done reading old hs

    // prefetch next step's gx in the MFMA shadow
    {
      int ssn = (ss + 1 < nsteps) ? (ss + 1) : ss;
      int ttn = fwd ? ssn : (nsteps - 1 - ssn);
#pragma unroll
      for (int j = 0; j < 3; ++j)
#pragma unroll
        for (int reg = 0; reg < 4; ++reg)
          gxn[j][reg] = buf[(size_t)((b0 + rq * 4 + reg) * TCH + ttn) * G3 + j * HID + hidx];
    }

    // G = h @ Whh^T, 3-term split
    float4v acc[3];
    acc[0] = (float4v)0.0f; acc[1] = (float4v)0.0f; acc[2] = (float4v)0.0f;
#pragma unroll
    for (int ks = 0; ks < 4; ++ks) {
#pragma unroll
      for (int j = 0; j < 3; ++j) {
        acc[j] = __builtin_amdgcn_mfma_f32_16x16x32_bf16(ah[ks], Bh[j][ks], acc[j], 0, 0, 0);
        acc[j] = __builtin_amdgcn_mfma_f32_16x16x32_bf16(ah[ks], Bl[j][ks], acc[j], 0, 0, 0);
        acc[j] = __builtin_amdgcn_mfma_f32_16x16x32_bf16(al[ks], Bh[j][ks], acc[j], 0, 0, 0);
      }
    }

    // activation + h update (all in-lane: r/z/n for (nb,hidx) share a lane)
#pragma unroll
    for (int reg = 0; reg < 4; ++reg) {
      int nb = rq * 4 + reg;
      float gr = acc[0][reg] + bias_[0] + gxc[0][reg];
      float gz = acc[1][reg] + bias_[1] + gxc[1][reg];
      float gn = acc[2][reg] + bias_[2];
      float xn = gxc[2][reg];
      float r = 1.0f / (1.0f + __expf(-gr));
      float z = 1.0f / (1.0f + __expf(-gz));
      float e2 = __expf(-2.0f * (xn + r * gn));
      float cand = (1.0f - e2) / (1.0f + e2);
      float hv = (1.0f - z) * cand + z * hold[reg];
      bool act = (t < len_[reg]);
      hv = act ? hv : hold[reg];
      hold[reg] = hv;
      unsigned short hh = f2bf_u(hv);
      hs_hi[nb * HSPAD + hidx] = hh;
      hs_lo[nb * HSPAD + hidx] = f2bf_u(hv - bfu2f(hh));
      if (act)
        rnn[(size_t)((b0 + nb) * SEQL + t) * OUTD + (fwd ? 0 : HID) + hidx] =
            __float2bfloat16(hv);
    }
    __syncthreads();   // hs ready; gxn loads drained (landed during MFMA+act)

#pragma unroll
    for (int j = 0; j < 3; ++j)
#pragma unroll
      for (int reg = 0; reg < 4; ++reg) gxc[j][reg] = gxn[j][reg];
  }

  // save h state (fp32 regs are the carrier)
#pragma unroll
  for (int reg = 0; reg < 4; ++reg)
    hst[(rq * 4 + reg) * HID + hidx] = hold[reg];
}

// ---- K3: scores via MFMA: A = rnn bf16, B = Wmlp hi/lo split; fused tanh+ctx epilogue ----
__global__ __launch_bounds__(256) void mlp_score(
    const __hip_bfloat16* __restrict__ rnn,
    const float* __restrict__ Wmlp, const float* __restrict__ bmlp,
    const float* __restrict__ ctx,
    float* __restrict__ scores)
{
  __shared__ unsigned short Abf[64 * 40];
  __shared__ unsigned short Bhi[256 * 40];
  __shared__ unsigned short Blo[256 * 40];

  const int tid = threadIdx.x;
  const int m0  = blockIdx.x * 64;
  const int l   = tid & 63;
  const int w   = tid >> 6;
  const int fr  = l & 15;
  const int fk  = (l >> 4) * 8;

  float bl_[16], cl_[16];
#pragma unroll
  for (int nt = 0; nt < 16; ++nt) {
    bl_[nt] = bmlp[nt * 16 + fr];
    cl_[nt] = ctx[nt * 16 + fr];
  }

  float4v acc[16];
#pragma unroll
  for (int nt = 0; nt < 16; ++nt) acc[nt] = (float4v)0.0f;

  for (int k0 = 0; k0 < OUTD; k0 += 32) {
    {
      int row = tid >> 2;
      int kq  = (tid & 3) * 8;
      *(short8v*)&Abf[row * 40 + kq] =
          *(const short8v*)((const short*)rnn + (size_t)(m0 + row) * OUTD + k0 + kq);
    }
#pragma unroll
    for (int j = 0; j < 8; ++j) {
      int col = (tid >> 3) + j * 32;
      int kq  = (tid & 7) * 4;
      float4 w4 = *(const float4*)&Wmlp[(size_t)col * OUTD + k0 + kq];
      unsigned short h0 = f2bf_u(w4.x), h1 = f2bf_u(w4.y), h2 = f2bf_u(w4.z), h3 = f2bf_u(w4.w);
      ushort4 hi4 = {h0, h1, h2, h3};
      ushort4 lo4 = {f2bf_u(w4.x - bfu2f(h0)), f2bf_u(w4.y - bfu2f(h1)),
                     f2bf_u(w4.z - bfu2f(h2)), f2bf_u(w4.w - bfu2f(h3))};
      *(ushort4*)&Bhi[col * 40 + kq] = hi4;
      *(ushort4*)&Blo[col * 40 + kq] = lo4;
    }
    __syncthreads();

    short8v a = *(const short8v*)&Abf[(w * 16 + fr) * 40 + fk];
#pragma unroll
    for (int nt = 0; nt < 16; ++nt) {
      short8v bh = *(const short8v*)&Bhi[(nt * 16 + fr) * 40 + fk];
      short8v bl = *(const short8v*)&Blo[(nt * 16 + fr) * 40 + fk];
      acc[nt] = __builtin_amdgcn_mfma_f32_16x16x32_bf16(a, bh, acc[nt], 0, 0, 0);
      acc[nt] = __builtin_amdgcn_mfma_f32_16x16x32_bf16(a, bl, acc[nt], 0, 0, 0);
    }
    __syncthreads();
  }

  float p[4] = {0.f, 0.f, 0.f, 0.f};
#pragma unroll
  for (int nt = 0; nt < 16; ++nt) {
    float bv_ = bl_[nt], cv = cl_[nt];
#pragma unroll
    for (int reg = 0; reg < 4; ++reg)
      p[reg] += tanhf(acc[nt][reg] + bv_) * cv;
  }
#pragma unroll
  for (int off = 1; off < 16; off <<= 1)
#pragma unroll
    for (int reg = 0; reg < 4; ++reg) p[reg] += __shfl_xor(p[reg], off, 64);

  if (fr == 0) {
#pragma unroll
    for (int reg = 0; reg < 4; ++reg)
      scores[m0 + w * 16 + (l >> 4) * 4 + reg] = p[reg];
  }
}

// ---- K4: masked softmax over l + weighted pool ----
__global__ __launch_bounds__(256) void softmax_pool(
    const int* __restrict__ seqlens,
    const float* __restrict__ scores,
    const __hip_bfloat16* __restrict__ rnn,
    float* __restrict__ out)
{
  const int b = blockIdx.x;
  const int len = seqlens[b];
  const int tid = threadIdx.x;
  __shared__ float sm[SEQL];
  __shared__ float red[8];

  float s = (tid < len) ? scores[b * SEQL + tid] : -3.4e38f;
  float wm = s;
#pragma unroll
  for (int off = 32; off > 0; off >>= 1) wm = fmaxf(wm, __shfl_xor(wm, off, 64));
  if ((tid & 63) == 0) red[tid >> 6] = wm;
  __syncthreads();
  float bm = fmaxf(fmaxf(red[0], red[1]), fmaxf(red[2], red[3]));

  float e = (tid < len) ? expf(s - bm) : 0.0f;
  sm[tid] = e;
  float sum = e;
#pragma unroll
  for (int off = 32; off > 0; off >>= 1) sum += __shfl_xor(sum, off, 64);
  if ((tid & 63) == 0) red[4 + (tid >> 6)] = sum;
  __syncthreads();
  float inv = 1.0f / (red[4] + red[5] + red[6] + red[7]);

  float acc = 0.0f;
  for (int l = 0; l < len; ++l)
    acc += sm[l] * __bfloat162float(rnn[(size_t)(b * SEQL + l) * OUTD + tid]);
  out[b * OUTD + tid] = acc * inv;
}

extern "C" void kernel_launch(void* const* d_in, const int* in_sizes, int n_in,
                              void* d_out, int out_size, void* d_ws, size_t ws_size,
                              hipStream_t stream) {
  const float* seq    = (const float*)d_in[0];
  const int*   lens   = (const int*)d_in[1];
  const float* Wih_f  = (const float*)d_in[2];
  const float* Whh_f  = (const float*)d_in[3];
  const float* bih_f  = (const float*)d_in[4];
  const float* bhh_f  = (const float*)d_in[5];
  const float* Wih_b  = (const float*)d_in[6];
  const float* Whh_b  = (const float*)d_in[7];
  const float* bih_b  = (const float*)d_in[8];
  const float* bhh_b  = (const float*)d_in[9];
  const float* Wmlp   = (const float*)d_in[10];
  const float* bmlp   = (const float*)d_in[11];
  const float* ctx    = (const float*)d_in[12];
  float* out = (float*)d_out;

  // ws layout: bufF 25.2MB | bufB 25.2MB | rnn bf16 67.1MB | scores 0.5MB | hstate 0.5MB
  float* bufF = (float*)d_ws;
  float* bufB = bufF + (size_t)MCH * G3;
  __hip_bfloat16* rnn = (__hip_bfloat16*)(bufB + (size_t)MCH * G3);
  float* scores = (float*)(rnn + (size_t)MTOT * OUTD);
  float* hstate = scores + MTOT;

  dim3 gG(MCH / 128, 12);
  for (int ci = 0; ci < NCH; ++ci) {
    gx_gemm_chunk<<<gG, 256, 0, stream>>>(seq, Wih_f, Wih_b, bih_f, bih_b,
                                          bufF, bufB, ci, NCH - 1 - ci);
    gru_scan_mfma<<<dim3(2 * NGRPS), 512, 0, stream>>>(
        lens, Whh_f, Whh_b, bhh_f, bhh_b, bufF, bufB, hstate, rnn, ci);
  }
  mlp_score<<<dim3(MTOT / 64), 256, 0, stream>>>(rnn, Wmlp, bmlp, ctx, scores);
  softmax_pool<<<dim3(BATCH), 256, 0, stream>>>(lens, scores, rnn, out);
}

// Round 6
// 874.461 us; speedup vs baseline: 6.9110x; 1.1121x over previous
//
#include <hip/hip_runtime.h>
#include <hip/hip_bf16.h>
#include <cstdint>
#include <cstddef>

#define BATCH 512
#define SEQL 256
#define DIN 256
#define HID 128
#define OUTD 256
#define G3 384            // 3*H
#define TCH 32            // time chunk
#define NCH 8             // SEQL / TCH
#define NBS 16            // batches per scan block
#define NGRPS (BATCH/NBS) // 32 groups per dir
#define MTOT (BATCH*SEQL) // 131072
#define MCH  (BATCH*TCH)  // 16384 rows per chunk per dir
#define HSPAD 136         // hs row pad (ushorts)

typedef __attribute__((ext_vector_type(8))) short short8v;
typedef __attribute__((ext_vector_type(4))) float float4v;

__device__ __forceinline__ unsigned short f2bf_u(float x) {
  union { float f; uint32_t u; } v; v.f = x;
  uint32_t r = v.u + 0x7FFFu + ((v.u >> 16) & 1u);
  return (unsigned short)(r >> 16);
}
__device__ __forceinline__ float bfu2f(unsigned short u) {
  union { uint32_t u; float f; } v; v.u = ((uint32_t)u) << 16; return v.f;
}
__device__ __forceinline__ float fast_tanh(float x) {
  float e2 = __expf(-2.0f * x);
  return (1.0f - e2) / (1.0f + e2);
}

// ---- K0: one-time Wmlp fp32 -> hi/lo bf16 split ----
__global__ __launch_bounds__(256) void prep_wmlp(
    const float* __restrict__ W,
    unsigned short* __restrict__ hi, unsigned short* __restrict__ lo)
{
  int idx = (blockIdx.x * 256 + threadIdx.x) * 4;   // 64 blocks cover 65536
  float4 w4 = *(const float4*)&W[idx];
  ushort4 h4, l4;
  h4.x = f2bf_u(w4.x); l4.x = f2bf_u(w4.x - bfu2f(h4.x));
  h4.y = f2bf_u(w4.y); l4.y = f2bf_u(w4.y - bfu2f(h4.y));
  h4.z = f2bf_u(w4.z); l4.z = f2bf_u(w4.z - bfu2f(h4.z));
  h4.w = f2bf_u(w4.w); l4.w = f2bf_u(w4.w - bfu2f(h4.w));
  *(ushort4*)&hi[idx] = h4;
  *(ushort4*)&lo[idx] = l4;
}

// ---- K1: chunked input GEMM via MFMA, 3-term bf16 split (fp32-class accuracy) ----
__global__ __launch_bounds__(256) void gx_gemm_chunk(
    const float* __restrict__ X,
    const float* __restrict__ Wf, const float* __restrict__ Wb,
    const float* __restrict__ bf, const float* __restrict__ bb,
    float* __restrict__ bufF, float* __restrict__ bufB, int cF, int cB)
{
  __shared__ unsigned short Ahi[128 * 40];
  __shared__ unsigned short Alo[128 * 40];
  __shared__ unsigned short Bhi[64 * 40];
  __shared__ unsigned short Blo[64 * 40];

  const int tid = threadIdx.x;
  const int m0  = blockIdx.x * 128;
  int yy = blockIdx.y;
  const float* W; const float* bias; float* buf; int c;
  if (yy < 6) { W = Wf; bias = bf; buf = bufF; c = cF; }
  else        { yy -= 6; W = Wb; bias = bb; buf = bufB; c = cB; }
  const int n0 = yy * 64;

  const int l  = tid & 63;
  const int w  = tid >> 6;
  const int fr = l & 15;
  const int fk = (l >> 4) * 8;

  float4v acc[2][4];
#pragma unroll
  for (int a = 0; a < 2; ++a)
#pragma unroll
    for (int nb = 0; nb < 4; ++nb) acc[a][nb] = (float4v)0.0f;

  for (int k0 = 0; k0 < DIN; k0 += 32) {
#pragma unroll
    for (int j = 0; j < 4; ++j) {
      int row = (tid >> 3) + j * 32;
      int kq  = (tid & 7) * 4;
      int r   = m0 + row;
      int b_  = r >> 5, tt = r & 31;
      int xrow = b_ * SEQL + c * TCH + tt;
      float4 x4 = *(const float4*)&X[(size_t)xrow * DIN + k0 + kq];
      unsigned short h0 = f2bf_u(x4.x), h1 = f2bf_u(x4.y), h2 = f2bf_u(x4.z), h3 = f2bf_u(x4.w);
      ushort4 hi4 = {h0, h1, h2, h3};
      ushort4 lo4 = {f2bf_u(x4.x - bfu2f(h0)), f2bf_u(x4.y - bfu2f(h1)),
                     f2bf_u(x4.z - bfu2f(h2)), f2bf_u(x4.w - bfu2f(h3))};
      *(ushort4*)&Ahi[row * 40 + kq] = hi4;
      *(ushort4*)&Alo[row * 40 + kq] = lo4;
    }
#pragma unroll
    for (int j = 0; j < 2; ++j) {
      int col = (tid >> 3) + j * 32;
      int kq  = (tid & 7) * 4;
      float4 w4 = *(const float4*)&W[(size_t)(n0 + col) * DIN + k0 + kq];
      unsigned short h0 = f2bf_u(w4.x), h1 = f2bf_u(w4.y), h2 = f2bf_u(w4.z), h3 = f2bf_u(w4.w);
      ushort4 hi4 = {h0, h1, h2, h3};
      ushort4 lo4 = {f2bf_u(w4.x - bfu2f(h0)), f2bf_u(w4.y - bfu2f(h1)),
                     f2bf_u(w4.z - bfu2f(h2)), f2bf_u(w4.w - bfu2f(h3))};
      *(ushort4*)&Bhi[col * 40 + kq] = hi4;
      *(ushort4*)&Blo[col * 40 + kq] = lo4;
    }
    __syncthreads();

    short8v ah[2], al[2], bh[4], blv[4];
#pragma unroll
    for (int a = 0; a < 2; ++a) {
      ah[a] = *(const short8v*)&Ahi[(w * 32 + a * 16 + fr) * 40 + fk];
      al[a] = *(const short8v*)&Alo[(w * 32 + a * 16 + fr) * 40 + fk];
    }
#pragma unroll
    for (int nb = 0; nb < 4; ++nb) {
      bh[nb]  = *(const short8v*)&Bhi[(nb * 16 + fr) * 40 + fk];
      blv[nb] = *(const short8v*)&Blo[(nb * 16 + fr) * 40 + fk];
    }
#pragma unroll
    for (int a = 0; a < 2; ++a)
#pragma unroll
      for (int nb = 0; nb < 4; ++nb) {
        acc[a][nb] = __builtin_amdgcn_mfma_f32_16x16x32_bf16(ah[a], bh[nb],  acc[a][nb], 0, 0, 0);
        acc[a][nb] = __builtin_amdgcn_mfma_f32_16x16x32_bf16(ah[a], blv[nb], acc[a][nb], 0, 0, 0);
        acc[a][nb] = __builtin_amdgcn_mfma_f32_16x16x32_bf16(al[a], bh[nb],  acc[a][nb], 0, 0, 0);
      }
    __syncthreads();
  }

#pragma unroll
  for (int a = 0; a < 2; ++a)
#pragma unroll
    for (int nb = 0; nb < 4; ++nb) {
      int gate = n0 + nb * 16 + fr;
      float bv_ = bias[gate];
#pragma unroll
      for (int reg = 0; reg < 4; ++reg) {
        int r = m0 + w * 32 + a * 16 + (l >> 4) * 4 + reg;
        buf[(size_t)r * G3 + gate] = acc[a][nb][reg] + bv_;
      }
    }
}

// ---- K2: MFMA GRU scan (unchanged from round 5) ----
__global__ __launch_bounds__(512, 2) void gru_scan_mfma(
    const int* __restrict__ seqlens,
    const float* __restrict__ Whh_f, const float* __restrict__ Whh_b,
    const float* __restrict__ bhh_f, const float* __restrict__ bhh_b,
    const float* __restrict__ bufF, const float* __restrict__ bufB,
    float* __restrict__ hstate, __hip_bfloat16* __restrict__ rnn, int ci)
{
  const int fwd = (blockIdx.x < NGRPS) ? 1 : 0;
  const int grp = fwd ? blockIdx.x : (blockIdx.x - NGRPS);
  const int b0  = grp * NBS;
  const int tid = threadIdx.x;
  const int w   = tid >> 6;
  const int l   = tid & 63;
  const int col = l & 15;
  const int rq  = l >> 4;
  const int hidx = w * 16 + col;
  const float* Whh = fwd ? Whh_f : Whh_b;
  const float* bhh = fwd ? bhh_f : bhh_b;
  const float* buf = fwd ? bufF : bufB;
  const int c = fwd ? ci : (NCH - 1 - ci);

  __shared__ unsigned short hs_hi[NBS * HSPAD];
  __shared__ unsigned short hs_lo[NBS * HSPAD];

  short8v Bh[3][4], Bl[3][4];
  float bias_[3];
#pragma unroll
  for (int j = 0; j < 3; ++j) {
    const int g = j * HID + hidx;
    bias_[j] = bhh[g];
#pragma unroll
    for (int ks = 0; ks < 4; ++ks) {
      const float* p = Whh + (size_t)g * HID + ks * 32 + rq * 8;
      float4 x0 = *(const float4*)p;
      float4 x1 = *(const float4*)(p + 4);
      float v[8] = {x0.x, x0.y, x0.z, x0.w, x1.x, x1.y, x1.z, x1.w};
      short8v hi8, lo8;
#pragma unroll
      for (int e = 0; e < 8; ++e) {
        unsigned short h = f2bf_u(v[e]);
        hi8[e] = (short)h;
        lo8[e] = (short)f2bf_u(v[e] - bfu2f(h));
      }
      Bh[j][ks] = hi8; Bl[j][ks] = lo8;
    }
  }

  int len_[4];
#pragma unroll
  for (int reg = 0; reg < 4; ++reg) len_[reg] = seqlens[b0 + rq * 4 + reg];
  int gmax = 0;
  for (int nb = 0; nb < NBS; ++nb) gmax = max(gmax, seqlens[b0 + nb]);

  float* hst = hstate + ((size_t)((fwd ? 0 : 1) * NGRPS + grp)) * (NBS * HID);
  float hold[4];
#pragma unroll
  for (int reg = 0; reg < 4; ++reg) {
    int nb = rq * 4 + reg;
    hold[reg] = (ci == 0) ? 0.0f : hst[nb * HID + hidx];
    unsigned short hh = f2bf_u(hold[reg]);
    hs_hi[nb * HSPAD + hidx] = hh;
    hs_lo[nb * HSPAD + hidx] = f2bf_u(hold[reg] - bfu2f(hh));
  }
  __syncthreads();

  int nsteps = gmax - c * TCH;
  nsteps = (nsteps > TCH) ? TCH : nsteps;

  float gxc[3][4], gxn[3][4];
  if (nsteps > 0) {
    int tt0 = fwd ? 0 : (nsteps - 1);
#pragma unroll
    for (int j = 0; j < 3; ++j)
#pragma unroll
      for (int reg = 0; reg < 4; ++reg)
        gxc[j][reg] = buf[(size_t)((b0 + rq * 4 + reg) * TCH + tt0) * G3 + j * HID + hidx];
  }

  for (int ss = 0; ss < nsteps; ++ss) {
    const int tt = fwd ? ss : (nsteps - 1 - ss);
    const int t  = c * TCH + tt;

    short8v ah[4], al[4];
#pragma unroll
    for (int ks = 0; ks < 4; ++ks) {
      ah[ks] = *(const short8v*)&hs_hi[col * HSPAD + ks * 32 + rq * 8];
      al[ks] = *(const short8v*)&hs_lo[col * HSPAD + ks * 32 + rq * 8];
    }
    __syncthreads();

    {
      int ssn = (ss + 1 < nsteps) ? (ss + 1) : ss;
      int ttn = fwd ? ssn : (nsteps - 1 - ssn);
#pragma unroll
      for (int j = 0; j < 3; ++j)
#pragma unroll
        for (int reg = 0; reg < 4; ++reg)
          gxn[j][reg] = buf[(size_t)((b0 + rq * 4 + reg) * TCH + ttn) * G3 + j * HID + hidx];
    }

    float4v acc[3];
    acc[0] = (float4v)0.0f; acc[1] = (float4v)0.0f; acc[2] = (float4v)0.0f;
#pragma unroll
    for (int ks = 0; ks < 4; ++ks) {
#pragma unroll
      for (int j = 0; j < 3; ++j) {
        acc[j] = __builtin_amdgcn_mfma_f32_16x16x32_bf16(ah[ks], Bh[j][ks], acc[j], 0, 0, 0);
        acc[j] = __builtin_amdgcn_mfma_f32_16x16x32_bf16(ah[ks], Bl[j][ks], acc[j], 0, 0, 0);
        acc[j] = __builtin_amdgcn_mfma_f32_16x16x32_bf16(al[ks], Bh[j][ks], acc[j], 0, 0, 0);
      }
    }

#pragma unroll
    for (int reg = 0; reg < 4; ++reg) {
      int nb = rq * 4 + reg;
      float gr = acc[0][reg] + bias_[0] + gxc[0][reg];
      float gz = acc[1][reg] + bias_[1] + gxc[1][reg];
      float gn = acc[2][reg] + bias_[2];
      float xn = gxc[2][reg];
      float r = 1.0f / (1.0f + __expf(-gr));
      float z = 1.0f / (1.0f + __expf(-gz));
      float e2 = __expf(-2.0f * (xn + r * gn));
      float cand = (1.0f - e2) / (1.0f + e2);
      float hv = (1.0f - z) * cand + z * hold[reg];
      bool act = (t < len_[reg]);
      hv = act ? hv : hold[reg];
      hold[reg] = hv;
      unsigned short hh = f2bf_u(hv);
      hs_hi[nb * HSPAD + hidx] = hh;
      hs_lo[nb * HSPAD + hidx] = f2bf_u(hv - bfu2f(hh));
      if (act)
        rnn[(size_t)((b0 + nb) * SEQL + t) * OUTD + (fwd ? 0 : HID) + hidx] =
            __float2bfloat16(hv);
    }
    __syncthreads();

#pragma unroll
    for (int j = 0; j < 3; ++j)
#pragma unroll
      for (int reg = 0; reg < 4; ++reg) gxc[j][reg] = gxn[j][reg];
  }

#pragma unroll
  for (int reg = 0; reg < 4; ++reg)
    hst[(rq * 4 + reg) * HID + hidx] = hold[reg];
}

// ---- K3 v2: scores via MFMA; B pre-split, M=128/block, single-copy staging ----
// grid 1024, 256 thr (4 waves). Wave w -> rows w*32..w*32+32 (2 tiles), all 16 col tiles.
__global__ __launch_bounds__(256) void mlp_score(
    const __hip_bfloat16* __restrict__ rnn,
    const unsigned short* __restrict__ Whi, const unsigned short* __restrict__ Wlo,
    const float* __restrict__ bmlp, const float* __restrict__ ctx,
    float* __restrict__ scores)
{
  __shared__ unsigned short Abf[128 * 40];   // 10 KB
  __shared__ unsigned short BhiS[256 * 40];  // 20 KB
  __shared__ unsigned short BloS[256 * 40];  // 20 KB

  const int tid = threadIdx.x;
  const int m0  = blockIdx.x * 128;
  const int l   = tid & 63;
  const int w   = tid >> 6;
  const int fr  = l & 15;
  const int fk  = (l >> 4) * 8;

  float bl_[16], cl_[16];
#pragma unroll
  for (int nt = 0; nt < 16; ++nt) {
    bl_[nt] = bmlp[nt * 16 + fr];
    cl_[nt] = ctx[nt * 16 + fr];
  }

  float4v acc[2][16];
#pragma unroll
  for (int a = 0; a < 2; ++a)
#pragma unroll
    for (int nt = 0; nt < 16; ++nt) acc[a][nt] = (float4v)0.0f;

  for (int k0 = 0; k0 < OUTD; k0 += 32) {
    // stage A: 128 rows x 32 k (bf16 direct, coalesced 32B/thread)
    {
      int row = tid >> 1;
      int kq  = (tid & 1) * 16;
      const short* src = (const short*)rnn + (size_t)(m0 + row) * OUTD + k0 + kq;
      *(short8v*)&Abf[row * 40 + kq]     = *(const short8v*)src;
      *(short8v*)&Abf[row * 40 + kq + 8] = *(const short8v*)(src + 8);
    }
    // stage B: 256 cols x 32 k, plain copies of pre-split hi/lo
#pragma unroll
    for (int j = 0; j < 2; ++j) {
      int col = (tid >> 1) + j * 128;
      int kq  = (tid & 1) * 16;
      const unsigned short* sh = Whi + (size_t)col * OUTD + k0 + kq;
      const unsigned short* sl = Wlo + (size_t)col * OUTD + k0 + kq;
      *(short8v*)&BhiS[col * 40 + kq]     = *(const short8v*)sh;
      *(short8v*)&BhiS[col * 40 + kq + 8] = *(const short8v*)(sh + 8);
      *(short8v*)&BloS[col * 40 + kq]     = *(const short8v*)sl;
      *(short8v*)&BloS[col * 40 + kq + 8] = *(const short8v*)(sl + 8);
    }
    __syncthreads();

    short8v ah0 = *(const short8v*)&Abf[(w * 32 + fr) * 40 + fk];
    short8v ah1 = *(const short8v*)&Abf[(w * 32 + 16 + fr) * 40 + fk];
#pragma unroll
    for (int nt = 0; nt < 16; ++nt) {
      short8v bh = *(const short8v*)&BhiS[(nt * 16 + fr) * 40 + fk];
      short8v bv = *(const short8v*)&BloS[(nt * 16 + fr) * 40 + fk];
      acc[0][nt] = __builtin_amdgcn_mfma_f32_16x16x32_bf16(ah0, bh, acc[0][nt], 0, 0, 0);
      acc[0][nt] = __builtin_amdgcn_mfma_f32_16x16x32_bf16(ah0, bv, acc[0][nt], 0, 0, 0);
      acc[1][nt] = __builtin_amdgcn_mfma_f32_16x16x32_bf16(ah1, bh, acc[1][nt], 0, 0, 0);
      acc[1][nt] = __builtin_amdgcn_mfma_f32_16x16x32_bf16(ah1, bv, acc[1][nt], 0, 0, 0);
    }
    __syncthreads();
  }

  // epilogue: tanh + ctx dot + 16-lane reduce, per a-tile
#pragma unroll
  for (int a = 0; a < 2; ++a) {
    float p[4] = {0.f, 0.f, 0.f, 0.f};
#pragma unroll
    for (int nt = 0; nt < 16; ++nt) {
      float bv_ = bl_[nt], cv = cl_[nt];
#pragma unroll
      for (int reg = 0; reg < 4; ++reg)
        p[reg] += fast_tanh(acc[a][nt][reg] + bv_) * cv;
    }
#pragma unroll
    for (int off = 1; off < 16; off <<= 1)
#pragma unroll
      for (int reg = 0; reg < 4; ++reg) p[reg] += __shfl_xor(p[reg], off, 64);
    if (fr == 0) {
#pragma unroll
      for (int reg = 0; reg < 4; ++reg)
        scores[m0 + w * 32 + a * 16 + (l >> 4) * 4 + reg] = p[reg];
    }
  }
}

// ---- K4: masked softmax over l + weighted pool ----
__global__ __launch_bounds__(256) void softmax_pool(
    const int* __restrict__ seqlens,
    const float* __restrict__ scores,
    const __hip_bfloat16* __restrict__ rnn,
    float* __restrict__ out)
{
  const int b = blockIdx.x;
  const int len = seqlens[b];
  const int tid = threadIdx.x;
  __shared__ float sm[SEQL];
  __shared__ float red[8];

  float s = (tid < len) ? scores[b * SEQL + tid] : -3.4e38f;
  float wm = s;
#pragma unroll
  for (int off = 32; off > 0; off >>= 1) wm = fmaxf(wm, __shfl_xor(wm, off, 64));
  if ((tid & 63) == 0) red[tid >> 6] = wm;
  __syncthreads();
  float bm = fmaxf(fmaxf(red[0], red[1]), fmaxf(red[2], red[3]));

  float e = (tid < len) ? expf(s - bm) : 0.0f;
  sm[tid] = e;
  float sum = e;
#pragma unroll
  for (int off = 32; off > 0; off >>= 1) sum += __shfl_xor(sum, off, 64);
  if ((tid & 63) == 0) red[4 + (tid >> 6)] = sum;
  __syncthreads();
  float inv = 1.0f / (red[4] + red[5] + red[6] + red[7]);

  float acc = 0.0f;
  for (int l = 0; l < len; ++l)
    acc += sm[l] * __bfloat162float(rnn[(size_t)(b * SEQL + l) * OUTD + tid]);
  out[b * OUTD + tid] = acc * inv;
}

extern "C" void kernel_launch(void* const* d_in, const int* in_sizes, int n_in,
                              void* d_out, int out_size, void* d_ws, size_t ws_size,
                              hipStream_t stream) {
  const float* seq    = (const float*)d_in[0];
  const int*   lens   = (const int*)d_in[1];
  const float* Wih_f  = (const float*)d_in[2];
  const float* Whh_f  = (const float*)d_in[3];
  const float* bih_f  = (const float*)d_in[4];
  const float* bhh_f  = (const float*)d_in[5];
  const float* Wih_b  = (const float*)d_in[6];
  const float* Whh_b  = (const float*)d_in[7];
  const float* bih_b  = (const float*)d_in[8];
  const float* bhh_b  = (const float*)d_in[9];
  const float* Wmlp   = (const float*)d_in[10];
  const float* bmlp   = (const float*)d_in[11];
  const float* ctx    = (const float*)d_in[12];
  float* out = (float*)d_out;

  // ws: bufF 25.2MB | bufB 25.2MB | rnn bf16 67.1MB | scores 0.5MB | hstate 0.5MB | whi/wlo 0.25MB
  float* bufF = (float*)d_ws;
  float* bufB = bufF + (size_t)MCH * G3;
  __hip_bfloat16* rnn = (__hip_bfloat16*)(bufB + (size_t)MCH * G3);
  float* scores = (float*)(rnn + (size_t)MTOT * OUTD);
  float* hstate = scores + MTOT;
  unsigned short* whi = (unsigned short*)(hstate + 2 * BATCH * HID);
  unsigned short* wlo = whi + OUTD * OUTD;

  prep_wmlp<<<dim3(64), 256, 0, stream>>>(Wmlp, whi, wlo);

  dim3 gG(MCH / 128, 12);
  for (int ci = 0; ci < NCH; ++ci) {
    gx_gemm_chunk<<<gG, 256, 0, stream>>>(seq, Wih_f, Wih_b, bih_f, bih_b,
                                          bufF, bufB, ci, NCH - 1 - ci);
    gru_scan_mfma<<<dim3(2 * NGRPS), 512, 0, stream>>>(
        lens, Whh_f, Whh_b, bhh_f, bhh_b, bufF, bufB, hstate, rnn, ci);
  }
  mlp_score<<<dim3(MTOT / 128), 256, 0, stream>>>(rnn, whi, wlo, bmlp, ctx, scores);
  softmax_pool<<<dim3(BATCH), 256, 0, stream>>>(lens, scores, rnn, out);
}

// Round 8
// 774.989 us; speedup vs baseline: 7.7980x; 1.1284x over previous
//
#include <hip/hip_runtime.h>
#include <hip/hip_bf16.h>
#include <cstdint>
#include <cstddef>

#define BATCH 512
#define SEQL 256
#define DIN 256
#define HID 128
#define OUTD 256
#define G3 384            // 3*H
#define TCH 64            // time chunk
#define NCH 4             // SEQL / TCH
#define NBS 16            // batches per scan block
#define NGRPS (BATCH/NBS) // 32 groups per dir
#define MTOT (BATCH*SEQL) // 131072
#define MCH  (BATCH*TCH)  // 32768 rows per chunk per dir
#define HSPAD 136         // hs row pad (ushorts)

typedef __attribute__((ext_vector_type(8))) short short8v;
typedef __attribute__((ext_vector_type(4))) float float4v;

__device__ __forceinline__ unsigned short f2bf_u(float x) {
  union { float f; uint32_t u; } v; v.f = x;
  uint32_t r = v.u + 0x7FFFu + ((v.u >> 16) & 1u);
  return (unsigned short)(r >> 16);
}
__device__ __forceinline__ float bfu2f(unsigned short u) {
  union { uint32_t u; float f; } v; v.u = ((uint32_t)u) << 16; return v.f;
}
__device__ __forceinline__ float fast_tanh(float x) {
  float e2 = __expf(-2.0f * x);
  return (1.0f - e2) / (1.0f + e2);
}

// ---- K0: one-time fp32 -> hi/lo bf16 split for Wmlp (65536), Wih_f, Wih_b (98304 each) ----
__global__ __launch_bounds__(256) void prep_split(
    const float* __restrict__ Wm, unsigned short* __restrict__ mhi, unsigned short* __restrict__ mlo,
    const float* __restrict__ Wf, unsigned short* __restrict__ fhi, unsigned short* __restrict__ flo,
    const float* __restrict__ Wb, unsigned short* __restrict__ bhi, unsigned short* __restrict__ blo)
{
  int gid = blockIdx.x * 256 + threadIdx.x;     // 65536 threads
  const float* src; unsigned short* hi; unsigned short* lo; int off;
  if (gid < 16384)      { src = Wm; hi = mhi; lo = mlo; off = gid * 4; }
  else if (gid < 40960) { src = Wf; hi = fhi; lo = flo; off = (gid - 16384) * 4; }
  else                  { src = Wb; hi = bhi; lo = blo; off = (gid - 40960) * 4; }
  float4 w4 = *(const float4*)&src[off];
  ushort4 h4, l4;
  h4.x = f2bf_u(w4.x); l4.x = f2bf_u(w4.x - bfu2f(h4.x));
  h4.y = f2bf_u(w4.y); l4.y = f2bf_u(w4.y - bfu2f(h4.y));
  h4.z = f2bf_u(w4.z); l4.z = f2bf_u(w4.z - bfu2f(h4.z));
  h4.w = f2bf_u(w4.w); l4.w = f2bf_u(w4.w - bfu2f(h4.w));
  *(ushort4*)&hi[off] = h4;
  *(ushort4*)&lo[off] = l4;
}

// ---- K1 v2: chunked input GEMM. A = X as plain bf16, B = pre-split Wih hi/lo (2-term).
// grid (MCH/128=256, 12): y<6 fwd N-tile(64), y>=6 bwd. Output bf16 buf.
__global__ __launch_bounds__(256) void gx_gemm_chunk(
    const float* __restrict__ X,
    const unsigned short* __restrict__ WhiF, const unsigned short* __restrict__ WloF,
    const unsigned short* __restrict__ WhiB, const unsigned short* __restrict__ WloB,
    const float* __restrict__ bf, const float* __restrict__ bb,
    unsigned short* __restrict__ bufF, unsigned short* __restrict__ bufB, int cF, int cB)
{
  __shared__ unsigned short Abf[128 * 40];   // 10 KB
  __shared__ unsigned short Bhi[64 * 40];    // 5 KB
  __shared__ unsigned short Blo[64 * 40];    // 5 KB

  const int tid = threadIdx.x;
  const int m0  = blockIdx.x * 128;
  int yy = blockIdx.y;
  const unsigned short* Whi; const unsigned short* Wlo;
  const float* bias; unsigned short* buf; int c;
  if (yy < 6) { Whi = WhiF; Wlo = WloF; bias = bf; buf = bufF; c = cF; }
  else        { yy -= 6; Whi = WhiB; Wlo = WloB; bias = bb; buf = bufB; c = cB; }
  const int n0 = yy * 64;

  const int l  = tid & 63;
  const int w  = tid >> 6;
  const int fr = l & 15;
  const int fk = (l >> 4) * 8;

  float4v acc[2][4];
#pragma unroll
  for (int a = 0; a < 2; ++a)
#pragma unroll
    for (int nb = 0; nb < 4; ++nb) acc[a][nb] = (float4v)0.0f;

  for (int k0 = 0; k0 < DIN; k0 += 32) {
    // stage A: 128 rows x 32 k, fp32 -> bf16 (plain, rounded)
#pragma unroll
    for (int j = 0; j < 4; ++j) {
      int row = (tid >> 3) + j * 32;
      int kq  = (tid & 7) * 4;
      int r   = m0 + row;
      int b_  = r >> 6, tt = r & 63;          // TCH = 64
      int xrow = b_ * SEQL + c * TCH + tt;
      float4 x4 = *(const float4*)&X[(size_t)xrow * DIN + k0 + kq];
      ushort4 h4 = {f2bf_u(x4.x), f2bf_u(x4.y), f2bf_u(x4.z), f2bf_u(x4.w)};
      *(ushort4*)&Abf[row * 40 + kq] = h4;
    }
    // stage B: 64 cols x 32 k, plain copies of pre-split hi/lo.
    // 256 tasks = {hi/lo} x {64 cols} x {seg 0/16}; each task copies 16 ushorts.
    {
      int half = tid & 1;                     // 0 = hi, 1 = lo
      int cc   = tid >> 1;                    // 0..127
      int col  = cc >> 1;                     // 0..63
      int seg  = (cc & 1) * 16;               // 0 or 16
      const unsigned short* srcw = (half ? Wlo : Whi) + (size_t)(n0 + col) * DIN + k0 + seg;
      unsigned short* dst = (half ? Blo : Bhi) + col * 40 + seg;
      *(short8v*)dst       = *(const short8v*)srcw;
      *(short8v*)(dst + 8) = *(const short8v*)(srcw + 8);
    }
    __syncthreads();

    short8v ah[2], bh[4], blv[4];
#pragma unroll
    for (int a = 0; a < 2; ++a)
      ah[a] = *(const short8v*)&Abf[(w * 32 + a * 16 + fr) * 40 + fk];
#pragma unroll
    for (int nb = 0; nb < 4; ++nb) {
      bh[nb]  = *(const short8v*)&Bhi[(nb * 16 + fr) * 40 + fk];
      blv[nb] = *(const short8v*)&Blo[(nb * 16 + fr) * 40 + fk];
    }
#pragma unroll
    for (int a = 0; a < 2; ++a)
#pragma unroll
      for (int nb = 0; nb < 4; ++nb) {
        acc[a][nb] = __builtin_amdgcn_mfma_f32_16x16x32_bf16(ah[a], bh[nb],  acc[a][nb], 0, 0, 0);
        acc[a][nb] = __builtin_amdgcn_mfma_f32_16x16x32_bf16(ah[a], blv[nb], acc[a][nb], 0, 0, 0);
      }
    __syncthreads();
  }

  // epilogue: + bias, write bf16 buf
#pragma unroll
  for (int a = 0; a < 2; ++a)
#pragma unroll
    for (int nb = 0; nb < 4; ++nb) {
      int gate = n0 + nb * 16 + fr;
      float bv_ = bias[gate];
#pragma unroll
      for (int reg = 0; reg < 4; ++reg) {
        int r = m0 + w * 32 + a * 16 + (l >> 4) * 4 + reg;
        buf[(size_t)r * G3 + gate] = f2bf_u(acc[a][nb][reg] + bv_);
      }
    }
}

// ---- K2: MFMA GRU scan (TCH=64, bf16 gx buf). 64 blocks, 512 thr. ----
__global__ __launch_bounds__(512, 2) void gru_scan_mfma(
    const int* __restrict__ seqlens,
    const float* __restrict__ Whh_f, const float* __restrict__ Whh_b,
    const float* __restrict__ bhh_f, const float* __restrict__ bhh_b,
    const unsigned short* __restrict__ bufF, const unsigned short* __restrict__ bufB,
    float* __restrict__ hstate, __hip_bfloat16* __restrict__ rnn, int ci)
{
  const int fwd = (blockIdx.x < NGRPS) ? 1 : 0;
  const int grp = fwd ? blockIdx.x : (blockIdx.x - NGRPS);
  const int b0  = grp * NBS;
  const int tid = threadIdx.x;
  const int w   = tid >> 6;
  const int l   = tid & 63;
  const int col = l & 15;
  const int rq  = l >> 4;
  const int hidx = w * 16 + col;
  const float* Whh = fwd ? Whh_f : Whh_b;
  const float* bhh = fwd ? bhh_f : bhh_b;
  const unsigned short* buf = fwd ? bufF : bufB;
  const int c = fwd ? ci : (NCH - 1 - ci);

  __shared__ unsigned short hs_hi[NBS * HSPAD];
  __shared__ unsigned short hs_lo[NBS * HSPAD];

  short8v Bh[3][4], Bl[3][4];
  float bias_[3];
#pragma unroll
  for (int j = 0; j < 3; ++j) {
    const int g = j * HID + hidx;
    bias_[j] = bhh[g];
#pragma unroll
    for (int ks = 0; ks < 4; ++ks) {
      const float* p = Whh + (size_t)g * HID + ks * 32 + rq * 8;
      float4 x0 = *(const float4*)p;
      float4 x1 = *(const float4*)(p + 4);
      float v[8] = {x0.x, x0.y, x0.z, x0.w, x1.x, x1.y, x1.z, x1.w};
      short8v hi8, lo8;
#pragma unroll
      for (int e = 0; e < 8; ++e) {
        unsigned short h = f2bf_u(v[e]);
        hi8[e] = (short)h;
        lo8[e] = (short)f2bf_u(v[e] - bfu2f(h));
      }
      Bh[j][ks] = hi8; Bl[j][ks] = lo8;
    }
  }

  int len_[4];
#pragma unroll
  for (int reg = 0; reg < 4; ++reg) len_[reg] = seqlens[b0 + rq * 4 + reg];
  int gmax = 0;
  for (int nb = 0; nb < NBS; ++nb) gmax = max(gmax, seqlens[b0 + nb]);

  float* hst = hstate + ((size_t)((fwd ? 0 : 1) * NGRPS + grp)) * (NBS * HID);
  float hold[4];
#pragma unroll
  for (int reg = 0; reg < 4; ++reg) {
    int nb = rq * 4 + reg;
    hold[reg] = (ci == 0) ? 0.0f : hst[nb * HID + hidx];
    unsigned short hh = f2bf_u(hold[reg]);
    hs_hi[nb * HSPAD + hidx] = hh;
    hs_lo[nb * HSPAD + hidx] = f2bf_u(hold[reg] - bfu2f(hh));
  }
  __syncthreads();

  int nsteps = gmax - c * TCH;
  nsteps = (nsteps > TCH) ? TCH : nsteps;

  float gxc[3][4], gxn[3][4];
  if (nsteps > 0) {
    int tt0 = fwd ? 0 : (nsteps - 1);
#pragma unroll
    for (int j = 0; j < 3; ++j)
#pragma unroll
      for (int reg = 0; reg < 4; ++reg)
        gxc[j][reg] = bfu2f(buf[(size_t)((b0 + rq * 4 + reg) * TCH + tt0) * G3 + j * HID + hidx]);
  }

  for (int ss = 0; ss < nsteps; ++ss) {
    const int tt = fwd ? ss : (nsteps - 1 - ss);
    const int t  = c * TCH + tt;

    short8v ah[4], al[4];
#pragma unroll
    for (int ks = 0; ks < 4; ++ks) {
      ah[ks] = *(const short8v*)&hs_hi[col * HSPAD + ks * 32 + rq * 8];
      al[ks] = *(const short8v*)&hs_lo[col * HSPAD + ks * 32 + rq * 8];
    }
    __syncthreads();

    {
      int ssn = (ss + 1 < nsteps) ? (ss + 1) : ss;
      int ttn = fwd ? ssn : (nsteps - 1 - ssn);
#pragma unroll
      for (int j = 0; j < 3; ++j)
#pragma unroll
        for (int reg = 0; reg < 4; ++reg)
          gxn[j][reg] = bfu2f(buf[(size_t)((b0 + rq * 4 + reg) * TCH + ttn) * G3 + j * HID + hidx]);
    }

    float4v acc[3];
    acc[0] = (float4v)0.0f; acc[1] = (float4v)0.0f; acc[2] = (float4v)0.0f;
#pragma unroll
    for (int ks = 0; ks < 4; ++ks) {
#pragma unroll
      for (int j = 0; j < 3; ++j) {
        acc[j] = __builtin_amdgcn_mfma_f32_16x16x32_bf16(ah[ks], Bh[j][ks], acc[j], 0, 0, 0);
        acc[j] = __builtin_amdgcn_mfma_f32_16x16x32_bf16(ah[ks], Bl[j][ks], acc[j], 0, 0, 0);
        acc[j] = __builtin_amdgcn_mfma_f32_16x16x32_bf16(al[ks], Bh[j][ks], acc[j], 0, 0, 0);
      }
    }

#pragma unroll
    for (int reg = 0; reg < 4; ++reg) {
      int nb = rq * 4 + reg;
      float gr = acc[0][reg] + bias_[0] + gxc[0][reg];
      float gz = acc[1][reg] + bias_[1] + gxc[1][reg];
      float gn = acc[2][reg] + bias_[2];
      float xn = gxc[2][reg];
      float r = 1.0f / (1.0f + __expf(-gr));
      float z = 1.0f / (1.0f + __expf(-gz));
      float e2 = __expf(-2.0f * (xn + r * gn));
      float cand = (1.0f - e2) / (1.0f + e2);
      float hv = (1.0f - z) * cand + z * hold[reg];
      bool act = (t < len_[reg]);
      hv = act ? hv : hold[reg];
      hold[reg] = hv;
      unsigned short hh = f2bf_u(hv);
      hs_hi[nb * HSPAD + hidx] = hh;
      hs_lo[nb * HSPAD + hidx] = f2bf_u(hv - bfu2f(hh));
      if (act)
        rnn[(size_t)((b0 + nb) * SEQL + t) * OUTD + (fwd ? 0 : HID) + hidx] =
            __float2bfloat16(hv);
    }
    __syncthreads();

#pragma unroll
    for (int j = 0; j < 3; ++j)
#pragma unroll
      for (int reg = 0; reg < 4; ++reg) gxc[j][reg] = gxn[j][reg];
  }

#pragma unroll
  for (int reg = 0; reg < 4; ++reg)
    hst[(rq * 4 + reg) * HID + hidx] = hold[reg];
}

// ---- K3 v4: scores via MFMA, N split in 2 halves. grid (1024, 2), 256 thr. ----
// Block: 128 rows x 128 cols (half of OUTD). acc[2][8]=64 VGPR, LDS 30KB.
__global__ __launch_bounds__(256) void mlp_score(
    const __hip_bfloat16* __restrict__ rnn,
    const unsigned short* __restrict__ Whi, const unsigned short* __restrict__ Wlo,
    const float* __restrict__ bmlp, const float* __restrict__ ctx,
    float* __restrict__ scoresH)
{
  __shared__ unsigned short Abf[128 * 40];   // 10 KB
  __shared__ unsigned short BhiS[128 * 40];  // 10 KB
  __shared__ unsigned short BloS[128 * 40];  // 10 KB

  const int tid = threadIdx.x;
  const int m0  = blockIdx.x * 128;
  const int nh  = blockIdx.y;                // 0 or 1: output cols nh*128..
  const int l   = tid & 63;
  const int w   = tid >> 6;
  const int fr  = l & 15;
  const int fk  = (l >> 4) * 8;

  float bl_[8], cl_[8];
#pragma unroll
  for (int nt = 0; nt < 8; ++nt) {
    bl_[nt] = bmlp[nh * 128 + nt * 16 + fr];
    cl_[nt] = ctx[nh * 128 + nt * 16 + fr];
  }

  float4v acc[2][8];
#pragma unroll
  for (int a = 0; a < 2; ++a)
#pragma unroll
    for (int nt = 0; nt < 8; ++nt) acc[a][nt] = (float4v)0.0f;

  for (int k0 = 0; k0 < OUTD; k0 += 32) {
    // stage A: 128 rows x 32 k
    {
      int row = tid >> 1;
      int kq  = (tid & 1) * 16;
      const short* src = (const short*)rnn + (size_t)(m0 + row) * OUTD + k0 + kq;
      *(short8v*)&Abf[row * 40 + kq]     = *(const short8v*)src;
      *(short8v*)&Abf[row * 40 + kq + 8] = *(const short8v*)(src + 8);
    }
    // stage B: 128 cols x 32 k, hi+lo = 512 tasks; each task copies 16 ushorts.
#pragma unroll
    for (int j = 0; j < 2; ++j) {
      int cid  = tid * 2 + j;          // 0..511
      int half = cid >> 8;             // 0 = hi, 1 = lo
      int cc   = cid & 255;
      int colx = cc >> 1;              // 0..127
      int seg  = (cc & 1) * 16;        // 0 or 16
      const unsigned short* srcw = (half ? Wlo : Whi) + (size_t)(nh * 128 + colx) * OUTD + k0 + seg;
      unsigned short* dst = (half ? BloS : BhiS) + colx * 40 + seg;
      *(short8v*)dst       = *(const short8v*)srcw;
      *(short8v*)(dst + 8) = *(const short8v*)(srcw + 8);
    }
    __syncthreads();

    short8v ah0 = *(const short8v*)&Abf[(w * 32 + fr) * 40 + fk];
    short8v ah1 = *(const short8v*)&Abf[(w * 32 + 16 + fr) * 40 + fk];
#pragma unroll
    for (int nt = 0; nt < 8; ++nt) {
      short8v bh = *(const short8v*)&BhiS[(nt * 16 + fr) * 40 + fk];
      short8v bv = *(const short8v*)&BloS[(nt * 16 + fr) * 40 + fk];
      acc[0][nt] = __builtin_amdgcn_mfma_f32_16x16x32_bf16(ah0, bh, acc[0][nt], 0, 0, 0);
      acc[0][nt] = __builtin_amdgcn_mfma_f32_16x16x32_bf16(ah0, bv, acc[0][nt], 0, 0, 0);
      acc[1][nt] = __builtin_amdgcn_mfma_f32_16x16x32_bf16(ah1, bh, acc[1][nt], 0, 0, 0);
      acc[1][nt] = __builtin_amdgcn_mfma_f32_16x16x32_bf16(ah1, bv, acc[1][nt], 0, 0, 0);
    }
    __syncthreads();
  }

  // epilogue: tanh + ctx dot (this half) + 16-lane reduce
#pragma unroll
  for (int a = 0; a < 2; ++a) {
    float p[4] = {0.f, 0.f, 0.f, 0.f};
#pragma unroll
    for (int nt = 0; nt < 8; ++nt) {
      float bv_ = bl_[nt], cv = cl_[nt];
#pragma unroll
      for (int reg = 0; reg < 4; ++reg)
        p[reg] += fast_tanh(acc[a][nt][reg] + bv_) * cv;
    }
#pragma unroll
    for (int off = 1; off < 16; off <<= 1)
#pragma unroll
      for (int reg = 0; reg < 4; ++reg) p[reg] += __shfl_xor(p[reg], off, 64);
    if (fr == 0) {
#pragma unroll
      for (int reg = 0; reg < 4; ++reg)
        scoresH[(size_t)nh * MTOT + m0 + w * 32 + a * 16 + (l >> 4) * 4 + reg] = p[reg];
    }
  }
}

// ---- K4: masked softmax over l + weighted pool (scores = half0 + half1) ----
__global__ __launch_bounds__(256) void softmax_pool(
    const int* __restrict__ seqlens,
    const float* __restrict__ scoresH,
    const __hip_bfloat16* __restrict__ rnn,
    float* __restrict__ out)
{
  const int b = blockIdx.x;
  const int len = seqlens[b];
  const int tid = threadIdx.x;
  __shared__ float sm[SEQL];
  __shared__ float red[8];

  float s = (tid < len)
      ? (scoresH[b * SEQL + tid] + scoresH[(size_t)MTOT + b * SEQL + tid])
      : -3.4e38f;
  float wm = s;
#pragma unroll
  for (int off = 32; off > 0; off >>= 1) wm = fmaxf(wm, __shfl_xor(wm, off, 64));
  if ((tid & 63) == 0) red[tid >> 6] = wm;
  __syncthreads();
  float bm = fmaxf(fmaxf(red[0], red[1]), fmaxf(red[2], red[3]));

  float e = (tid < len) ? expf(s - bm) : 0.0f;
  sm[tid] = e;
  float sum = e;
#pragma unroll
  for (int off = 32; off > 0; off >>= 1) sum += __shfl_xor(sum, off, 64);
  if ((tid & 63) == 0) red[4 + (tid >> 6)] = sum;
  __syncthreads();
  float inv = 1.0f / (red[4] + red[5] + red[6] + red[7]);

  float acc = 0.0f;
  for (int l = 0; l < len; ++l)
    acc += sm[l] * __bfloat162float(rnn[(size_t)(b * SEQL + l) * OUTD + tid]);
  out[b * OUTD + tid] = acc * inv;
}

extern "C" void kernel_launch(void* const* d_in, const int* in_sizes, int n_in,
                              void* d_out, int out_size, void* d_ws, size_t ws_size,
                              hipStream_t stream) {
  const float* seq    = (const float*)d_in[0];
  const int*   lens   = (const int*)d_in[1];
  const float* Wih_f  = (const float*)d_in[2];
  const float* Whh_f  = (const float*)d_in[3];
  const float* bih_f  = (const float*)d_in[4];
  const float* bhh_f  = (const float*)d_in[5];
  const float* Wih_b  = (const float*)d_in[6];
  const float* Whh_b  = (const float*)d_in[7];
  const float* bih_b  = (const float*)d_in[8];
  const float* bhh_b  = (const float*)d_in[9];
  const float* Wmlp   = (const float*)d_in[10];
  const float* bmlp   = (const float*)d_in[11];
  const float* ctx    = (const float*)d_in[12];
  float* out = (float*)d_out;

  // ws (bytes): bufF 25.2M | bufB 25.2M | rnn 67.1M | scoresH 1.05M | hstate 0.52M |
  //             mhi/mlo 0.26M | fhi/flo/bhi/blo 0.79M   (total ~120.1 MB)
  unsigned short* bufF = (unsigned short*)d_ws;
  unsigned short* bufB = bufF + (size_t)MCH * G3;
  __hip_bfloat16* rnn  = (__hip_bfloat16*)(bufB + (size_t)MCH * G3);
  float* scoresH = (float*)((unsigned short*)rnn + (size_t)MTOT * OUTD);
  float* hstate  = scoresH + 2 * (size_t)MTOT;
  unsigned short* mhi = (unsigned short*)(hstate + 2 * BATCH * HID);
  unsigned short* mlo = mhi + OUTD * OUTD;
  unsigned short* fhi = mlo + OUTD * OUTD;
  unsigned short* flo = fhi + G3 * DIN;
  unsigned short* bhi2 = flo + G3 * DIN;
  unsigned short* blo2 = bhi2 + G3 * DIN;

  prep_split<<<dim3(256), 256, 0, stream>>>(Wmlp, mhi, mlo, Wih_f, fhi, flo, Wih_b, bhi2, blo2);

  dim3 gG(MCH / 128, 12);
  for (int ci = 0; ci < NCH; ++ci) {
    gx_gemm_chunk<<<gG, 256, 0, stream>>>(seq, fhi, flo, bhi2, blo2, bih_f, bih_b,
                                          bufF, bufB, ci, NCH - 1 - ci);
    gru_scan_mfma<<<dim3(2 * NGRPS), 512, 0, stream>>>(
        lens, Whh_f, Whh_b, bhh_f, bhh_b, bufF, bufB, hstate, rnn, ci);
  }
  mlp_score<<<dim3(MTOT / 128, 2), 256, 0, stream>>>(rnn, mhi, mlo, bmlp, ctx, scoresH);
  softmax_pool<<<dim3(BATCH), 256, 0, stream>>>(lens, scoresH, rnn, out);
}

// Round 9
// 697.022 us; speedup vs baseline: 8.6703x; 1.1119x over previous
//
#include <hip/hip_runtime.h>
#include <hip/hip_bf16.h>
#include <cstdint>
#include <cstddef>

#define BATCH 512
#define SEQL 256
#define DIN 256
#define HID 128
#define OUTD 256
#define G3 384            // 3*H
#define TCH 64            // time chunk
#define NCH 4             // SEQL / TCH
#define NBS 16            // batches per scan block
#define NGRPS (BATCH/NBS) // 32 groups per dir
#define MTOT (BATCH*SEQL) // 131072
#define MCH  (BATCH*TCH)  // 32768 rows per chunk per dir
#define HSPAD 136         // hs row pad (ushorts)

typedef __attribute__((ext_vector_type(8))) short short8v;
typedef __attribute__((ext_vector_type(4))) float float4v;

__device__ __forceinline__ unsigned short f2bf_u(float x) {
  union { float f; uint32_t u; } v; v.f = x;
  uint32_t r = v.u + 0x7FFFu + ((v.u >> 16) & 1u);
  return (unsigned short)(r >> 16);
}
__device__ __forceinline__ float bfu2f(unsigned short u) {
  union { uint32_t u; float f; } v; v.u = ((uint32_t)u) << 16; return v.f;
}
__device__ __forceinline__ float fast_tanh(float x) {
  float e2 = __expf(-2.0f * x);
  return (1.0f - e2) / (1.0f + e2);
}

// ---- K0: one-time fp32 -> hi/lo bf16 split for Wmlp (65536), Wih_f, Wih_b (98304 each) ----
__global__ __launch_bounds__(256) void prep_split(
    const float* __restrict__ Wm, unsigned short* __restrict__ mhi, unsigned short* __restrict__ mlo,
    const float* __restrict__ Wf, unsigned short* __restrict__ fhi, unsigned short* __restrict__ flo,
    const float* __restrict__ Wb, unsigned short* __restrict__ bhi, unsigned short* __restrict__ blo)
{
  int gid = blockIdx.x * 256 + threadIdx.x;     // 65536 threads
  const float* src; unsigned short* hi; unsigned short* lo; int off;
  if (gid < 16384)      { src = Wm; hi = mhi; lo = mlo; off = gid * 4; }
  else if (gid < 40960) { src = Wf; hi = fhi; lo = flo; off = (gid - 16384) * 4; }
  else                  { src = Wb; hi = bhi; lo = blo; off = (gid - 40960) * 4; }
  float4 w4 = *(const float4*)&src[off];
  ushort4 h4, l4;
  h4.x = f2bf_u(w4.x); l4.x = f2bf_u(w4.x - bfu2f(h4.x));
  h4.y = f2bf_u(w4.y); l4.y = f2bf_u(w4.y - bfu2f(h4.y));
  h4.z = f2bf_u(w4.z); l4.z = f2bf_u(w4.z - bfu2f(h4.z));
  h4.w = f2bf_u(w4.w); l4.w = f2bf_u(w4.w - bfu2f(h4.w));
  *(ushort4*)&hi[off] = h4;
  *(ushort4*)&lo[off] = l4;
}

// ---- K1 v2: chunked input GEMM. A = X as plain bf16, B = pre-split Wih hi/lo (2-term).
__global__ __launch_bounds__(256) void gx_gemm_chunk(
    const float* __restrict__ X,
    const unsigned short* __restrict__ WhiF, const unsigned short* __restrict__ WloF,
    const unsigned short* __restrict__ WhiB, const unsigned short* __restrict__ WloB,
    const float* __restrict__ bf, const float* __restrict__ bb,
    unsigned short* __restrict__ bufF, unsigned short* __restrict__ bufB, int cF, int cB)
{
  __shared__ unsigned short Abf[128 * 40];   // 10 KB
  __shared__ unsigned short Bhi[64 * 40];    // 5 KB
  __shared__ unsigned short Blo[64 * 40];    // 5 KB

  const int tid = threadIdx.x;
  const int m0  = blockIdx.x * 128;
  int yy = blockIdx.y;
  const unsigned short* Whi; const unsigned short* Wlo;
  const float* bias; unsigned short* buf; int c;
  if (yy < 6) { Whi = WhiF; Wlo = WloF; bias = bf; buf = bufF; c = cF; }
  else        { yy -= 6; Whi = WhiB; Wlo = WloB; bias = bb; buf = bufB; c = cB; }
  const int n0 = yy * 64;

  const int l  = tid & 63;
  const int w  = tid >> 6;
  const int fr = l & 15;
  const int fk = (l >> 4) * 8;

  float4v acc[2][4];
#pragma unroll
  for (int a = 0; a < 2; ++a)
#pragma unroll
    for (int nb = 0; nb < 4; ++nb) acc[a][nb] = (float4v)0.0f;

  for (int k0 = 0; k0 < DIN; k0 += 32) {
#pragma unroll
    for (int j = 0; j < 4; ++j) {
      int row = (tid >> 3) + j * 32;
      int kq  = (tid & 7) * 4;
      int r   = m0 + row;
      int b_  = r >> 6, tt = r & 63;          // TCH = 64
      int xrow = b_ * SEQL + c * TCH + tt;
      float4 x4 = *(const float4*)&X[(size_t)xrow * DIN + k0 + kq];
      ushort4 h4 = {f2bf_u(x4.x), f2bf_u(x4.y), f2bf_u(x4.z), f2bf_u(x4.w)};
      *(ushort4*)&Abf[row * 40 + kq] = h4;
    }
    {
      int half = tid & 1;
      int cc   = tid >> 1;
      int col  = cc >> 1;
      int seg  = (cc & 1) * 16;
      const unsigned short* srcw = (half ? Wlo : Whi) + (size_t)(n0 + col) * DIN + k0 + seg;
      unsigned short* dst = (half ? Blo : Bhi) + col * 40 + seg;
      *(short8v*)dst       = *(const short8v*)srcw;
      *(short8v*)(dst + 8) = *(const short8v*)(srcw + 8);
    }
    __syncthreads();

    short8v ah[2], bh[4], blv[4];
#pragma unroll
    for (int a = 0; a < 2; ++a)
      ah[a] = *(const short8v*)&Abf[(w * 32 + a * 16 + fr) * 40 + fk];
#pragma unroll
    for (int nb = 0; nb < 4; ++nb) {
      bh[nb]  = *(const short8v*)&Bhi[(nb * 16 + fr) * 40 + fk];
      blv[nb] = *(const short8v*)&Blo[(nb * 16 + fr) * 40 + fk];
    }
#pragma unroll
    for (int a = 0; a < 2; ++a)
#pragma unroll
      for (int nb = 0; nb < 4; ++nb) {
        acc[a][nb] = __builtin_amdgcn_mfma_f32_16x16x32_bf16(ah[a], bh[nb],  acc[a][nb], 0, 0, 0);
        acc[a][nb] = __builtin_amdgcn_mfma_f32_16x16x32_bf16(ah[a], blv[nb], acc[a][nb], 0, 0, 0);
      }
    __syncthreads();
  }

#pragma unroll
  for (int a = 0; a < 2; ++a)
#pragma unroll
    for (int nb = 0; nb < 4; ++nb) {
      int gate = n0 + nb * 16 + fr;
      float bv_ = bias[gate];
#pragma unroll
      for (int reg = 0; reg < 4; ++reg) {
        int r = m0 + w * 32 + a * 16 + (l >> 4) * 4 + reg;
        buf[(size_t)r * G3 + gate] = f2bf_u(acc[a][nb][reg] + bv_);
      }
    }
}

// ---- K2 v3: MFMA GRU scan. 2-term (W hi/lo), h plain bf16, ping-pong LDS, 1 barrier/step. ----
__global__ __launch_bounds__(512, 2) void gru_scan_mfma(
    const int* __restrict__ seqlens,
    const float* __restrict__ Whh_f, const float* __restrict__ Whh_b,
    const float* __restrict__ bhh_f, const float* __restrict__ bhh_b,
    const unsigned short* __restrict__ bufF, const unsigned short* __restrict__ bufB,
    float* __restrict__ hstate, __hip_bfloat16* __restrict__ rnn, int ci)
{
  const int fwd = (blockIdx.x < NGRPS) ? 1 : 0;
  const int grp = fwd ? blockIdx.x : (blockIdx.x - NGRPS);
  const int b0  = grp * NBS;
  const int tid = threadIdx.x;
  const int w   = tid >> 6;
  const int l   = tid & 63;
  const int col = l & 15;     // A-row (batch) / C-col (hidx) within wave tile
  const int rq  = l >> 4;     // k-slice / C row-quad (batches rq*4..rq*4+3)
  const int hidx = w * 16 + col;
  const float* Whh = fwd ? Whh_f : Whh_b;
  const float* bhh = fwd ? bhh_f : bhh_b;
  const unsigned short* buf = fwd ? bufF : bufB;
  const int c = fwd ? ci : (NCH - 1 - ci);

  __shared__ unsigned short hsbuf[2][NBS * HSPAD];

  // one-time: Whh B fragments (hi/lo) + bias
  short8v Bh[3][4], Bl[3][4];
  float bias_[3];
#pragma unroll
  for (int j = 0; j < 3; ++j) {
    const int g = j * HID + hidx;
    bias_[j] = bhh[g];
#pragma unroll
    for (int ks = 0; ks < 4; ++ks) {
      const float* p = Whh + (size_t)g * HID + ks * 32 + rq * 8;
      float4 x0 = *(const float4*)p;
      float4 x1 = *(const float4*)(p + 4);
      float v[8] = {x0.x, x0.y, x0.z, x0.w, x1.x, x1.y, x1.z, x1.w};
      short8v hi8, lo8;
#pragma unroll
      for (int e = 0; e < 8; ++e) {
        unsigned short h = f2bf_u(v[e]);
        hi8[e] = (short)h;
        lo8[e] = (short)f2bf_u(v[e] - bfu2f(h));
      }
      Bh[j][ks] = hi8; Bl[j][ks] = lo8;
    }
  }

  int len_[4];
#pragma unroll
  for (int reg = 0; reg < 4; ++reg) len_[reg] = seqlens[b0 + rq * 4 + reg];
  int gmax = 0;
  for (int nb = 0; nb < NBS; ++nb) gmax = max(gmax, seqlens[b0 + nb]);

  float* hst = hstate + ((size_t)((fwd ? 0 : 1) * NGRPS + grp)) * (NBS * HID);
  float hold[4];
#pragma unroll
  for (int reg = 0; reg < 4; ++reg) {
    int nb = rq * 4 + reg;
    hold[reg] = (ci == 0) ? 0.0f : hst[nb * HID + hidx];
    hsbuf[0][nb * HSPAD + hidx] = f2bf_u(hold[reg]);
  }
  __syncthreads();

  int nsteps = gmax - c * TCH;
  nsteps = (nsteps > TCH) ? TCH : nsteps;

  float gxc[3][4], gxn[3][4];
  if (nsteps > 0) {
    int tt0 = fwd ? 0 : (nsteps - 1);
#pragma unroll
    for (int j = 0; j < 3; ++j)
#pragma unroll
      for (int reg = 0; reg < 4; ++reg)
        gxc[j][reg] = bfu2f(buf[(size_t)((b0 + rq * 4 + reg) * TCH + tt0) * G3 + j * HID + hidx]);
  }

  int cur = 0;
  for (int ss = 0; ss < nsteps; ++ss) {
    const int tt = fwd ? ss : (nsteps - 1 - ss);
    const int t  = c * TCH + tt;

    // A-fragment reads from hsbuf[cur]
    short8v ah[4];
#pragma unroll
    for (int ks = 0; ks < 4; ++ks)
      ah[ks] = *(const short8v*)&hsbuf[cur][col * HSPAD + ks * 32 + rq * 8];

    // prefetch next step's gx (lands during MFMA phase)
    {
      int ssn = (ss + 1 < nsteps) ? (ss + 1) : ss;
      int ttn = fwd ? ssn : (nsteps - 1 - ssn);
#pragma unroll
      for (int j = 0; j < 3; ++j)
#pragma unroll
        for (int reg = 0; reg < 4; ++reg)
          gxn[j][reg] = bfu2f(buf[(size_t)((b0 + rq * 4 + reg) * TCH + ttn) * G3 + j * HID + hidx]);
    }

    // G = h @ Whh^T, 2-term (W hi + W lo), bias folded into acc init
    float4v acc[3];
#pragma unroll
    for (int j = 0; j < 3; ++j)
      acc[j] = (float4v){bias_[j], bias_[j], bias_[j], bias_[j]};
#pragma unroll
    for (int ks = 0; ks < 4; ++ks) {
#pragma unroll
      for (int j = 0; j < 3; ++j) {
        acc[j] = __builtin_amdgcn_mfma_f32_16x16x32_bf16(ah[ks], Bh[j][ks], acc[j], 0, 0, 0);
        acc[j] = __builtin_amdgcn_mfma_f32_16x16x32_bf16(ah[ks], Bl[j][ks], acc[j], 0, 0, 0);
      }
    }

    // activation + h update; write next-step h into hsbuf[cur^1]
#pragma unroll
    for (int reg = 0; reg < 4; ++reg) {
      int nb = rq * 4 + reg;
      float gr = acc[0][reg] + gxc[0][reg];
      float gz = acc[1][reg] + gxc[1][reg];
      float gn = acc[2][reg];
      float xn = gxc[2][reg];
      float r = 1.0f / (1.0f + __expf(-gr));
      float z = 1.0f / (1.0f + __expf(-gz));
      float e2 = __expf(-2.0f * (xn + r * gn));
      float cand = (1.0f - e2) / (1.0f + e2);
      float hv = (1.0f - z) * cand + z * hold[reg];
      bool act = (t < len_[reg]);
      hv = act ? hv : hold[reg];
      hold[reg] = hv;
      hsbuf[cur ^ 1][nb * HSPAD + hidx] = f2bf_u(hv);
      if (act)
        rnn[(size_t)((b0 + nb) * SEQL + t) * OUTD + (fwd ? 0 : HID) + hidx] =
            __float2bfloat16(hv);
    }
    __syncthreads();   // hsbuf[cur^1] complete; gxn drained during MFMA
    cur ^= 1;

#pragma unroll
    for (int j = 0; j < 3; ++j)
#pragma unroll
      for (int reg = 0; reg < 4; ++reg) gxc[j][reg] = gxn[j][reg];
  }

#pragma unroll
  for (int reg = 0; reg < 4; ++reg)
    hst[(rq * 4 + reg) * HID + hidx] = hold[reg];
}

// ---- K3 v4: scores via MFMA, N split in 2 halves. grid (1024, 2), 256 thr. ----
__global__ __launch_bounds__(256) void mlp_score(
    const __hip_bfloat16* __restrict__ rnn,
    const unsigned short* __restrict__ Whi, const unsigned short* __restrict__ Wlo,
    const float* __restrict__ bmlp, const float* __restrict__ ctx,
    float* __restrict__ scoresH)
{
  __shared__ unsigned short Abf[128 * 40];   // 10 KB
  __shared__ unsigned short BhiS[128 * 40];  // 10 KB
  __shared__ unsigned short BloS[128 * 40];  // 10 KB

  const int tid = threadIdx.x;
  const int m0  = blockIdx.x * 128;
  const int nh  = blockIdx.y;
  const int l   = tid & 63;
  const int w   = tid >> 6;
  const int fr  = l & 15;
  const int fk  = (l >> 4) * 8;

  float bl_[8], cl_[8];
#pragma unroll
  for (int nt = 0; nt < 8; ++nt) {
    bl_[nt] = bmlp[nh * 128 + nt * 16 + fr];
    cl_[nt] = ctx[nh * 128 + nt * 16 + fr];
  }

  float4v acc[2][8];
#pragma unroll
  for (int a = 0; a < 2; ++a)
#pragma unroll
    for (int nt = 0; nt < 8; ++nt) acc[a][nt] = (float4v)0.0f;

  for (int k0 = 0; k0 < OUTD; k0 += 32) {
    {
      int row = tid >> 1;
      int kq  = (tid & 1) * 16;
      const short* src = (const short*)rnn + (size_t)(m0 + row) * OUTD + k0 + kq;
      *(short8v*)&Abf[row * 40 + kq]     = *(const short8v*)src;
      *(short8v*)&Abf[row * 40 + kq + 8] = *(const short8v*)(src + 8);
    }
#pragma unroll
    for (int j = 0; j < 2; ++j) {
      int cid  = tid * 2 + j;
      int half = cid >> 8;
      int cc   = cid & 255;
      int colx = cc >> 1;
      int seg  = (cc & 1) * 16;
      const unsigned short* srcw = (half ? Wlo : Whi) + (size_t)(nh * 128 + colx) * OUTD + k0 + seg;
      unsigned short* dst = (half ? BloS : BhiS) + colx * 40 + seg;
      *(short8v*)dst       = *(const short8v*)srcw;
      *(short8v*)(dst + 8) = *(const short8v*)(srcw + 8);
    }
    __syncthreads();

    short8v ah0 = *(const short8v*)&Abf[(w * 32 + fr) * 40 + fk];
    short8v ah1 = *(const short8v*)&Abf[(w * 32 + 16 + fr) * 40 + fk];
#pragma unroll
    for (int nt = 0; nt < 8; ++nt) {
      short8v bh = *(const short8v*)&BhiS[(nt * 16 + fr) * 40 + fk];
      short8v bv = *(const short8v*)&BloS[(nt * 16 + fr) * 40 + fk];
      acc[0][nt] = __builtin_amdgcn_mfma_f32_16x16x32_bf16(ah0, bh, acc[0][nt], 0, 0, 0);
      acc[0][nt] = __builtin_amdgcn_mfma_f32_16x16x32_bf16(ah0, bv, acc[0][nt], 0, 0, 0);
      acc[1][nt] = __builtin_amdgcn_mfma_f32_16x16x32_bf16(ah1, bh, acc[1][nt], 0, 0, 0);
      acc[1][nt] = __builtin_amdgcn_mfma_f32_16x16x32_bf16(ah1, bv, acc[1][nt], 0, 0, 0);
    }
    __syncthreads();
  }

#pragma unroll
  for (int a = 0; a < 2; ++a) {
    float p[4] = {0.f, 0.f, 0.f, 0.f};
#pragma unroll
    for (int nt = 0; nt < 8; ++nt) {
      float bv_ = bl_[nt], cv = cl_[nt];
#pragma unroll
      for (int reg = 0; reg < 4; ++reg)
        p[reg] += fast_tanh(acc[a][nt][reg] + bv_) * cv;
    }
#pragma unroll
    for (int off = 1; off < 16; off <<= 1)
#pragma unroll
      for (int reg = 0; reg < 4; ++reg) p[reg] += __shfl_xor(p[reg], off, 64);
    if (fr == 0) {
#pragma unroll
      for (int reg = 0; reg < 4; ++reg)
        scoresH[(size_t)nh * MTOT + m0 + w * 32 + a * 16 + (l >> 4) * 4 + reg] = p[reg];
    }
  }
}

// ---- K4: masked softmax over l + weighted pool (scores = half0 + half1) ----
__global__ __launch_bounds__(256) void softmax_pool(
    const int* __restrict__ seqlens,
    const float* __restrict__ scoresH,
    const __hip_bfloat16* __restrict__ rnn,
    float* __restrict__ out)
{
  const int b = blockIdx.x;
  const int len = seqlens[b];
  const int tid = threadIdx.x;
  __shared__ float sm[SEQL];
  __shared__ float red[8];

  float s = (tid < len)
      ? (scoresH[b * SEQL + tid] + scoresH[(size_t)MTOT + b * SEQL + tid])
      : -3.4e38f;
  float wm = s;
#pragma unroll
  for (int off = 32; off > 0; off >>= 1) wm = fmaxf(wm, __shfl_xor(wm, off, 64));
  if ((tid & 63) == 0) red[tid >> 6] = wm;
  __syncthreads();
  float bm = fmaxf(fmaxf(red[0], red[1]), fmaxf(red[2], red[3]));

  float e = (tid < len) ? expf(s - bm) : 0.0f;
  sm[tid] = e;
  float sum = e;
#pragma unroll
  for (int off = 32; off > 0; off >>= 1) sum += __shfl_xor(sum, off, 64);
  if ((tid & 63) == 0) red[4 + (tid >> 6)] = sum;
  __syncthreads();
  float inv = 1.0f / (red[4] + red[5] + red[6] + red[7]);

  float acc = 0.0f;
  for (int l = 0; l < len; ++l)
    acc += sm[l] * __bfloat162float(rnn[(size_t)(b * SEQL + l) * OUTD + tid]);
  out[b * OUTD + tid] = acc * inv;
}

extern "C" void kernel_launch(void* const* d_in, const int* in_sizes, int n_in,
                              void* d_out, int out_size, void* d_ws, size_t ws_size,
                              hipStream_t stream) {
  const float* seq    = (const float*)d_in[0];
  const int*   lens   = (const int*)d_in[1];
  const float* Wih_f  = (const float*)d_in[2];
  const float* Whh_f  = (const float*)d_in[3];
  const float* bih_f  = (const float*)d_in[4];
  const float* bhh_f  = (const float*)d_in[5];
  const float* Wih_b  = (const float*)d_in[6];
  const float* Whh_b  = (const float*)d_in[7];
  const float* bih_b  = (const float*)d_in[8];
  const float* bhh_b  = (const float*)d_in[9];
  const float* Wmlp   = (const float*)d_in[10];
  const float* bmlp   = (const float*)d_in[11];
  const float* ctx    = (const float*)d_in[12];
  float* out = (float*)d_out;

  // ws: bufF 25.2M | bufB 25.2M | rnn 67.1M | scoresH 1.05M | hstate 0.52M | splits ~1.05M
  unsigned short* bufF = (unsigned short*)d_ws;
  unsigned short* bufB = bufF + (size_t)MCH * G3;
  __hip_bfloat16* rnn  = (__hip_bfloat16*)(bufB + (size_t)MCH * G3);
  float* scoresH = (float*)((unsigned short*)rnn + (size_t)MTOT * OUTD);
  float* hstate  = scoresH + 2 * (size_t)MTOT;
  unsigned short* mhi = (unsigned short*)(hstate + 2 * BATCH * HID);
  unsigned short* mlo = mhi + OUTD * OUTD;
  unsigned short* fhi = mlo + OUTD * OUTD;
  unsigned short* flo = fhi + G3 * DIN;
  unsigned short* bhi2 = flo + G3 * DIN;
  unsigned short* blo2 = bhi2 + G3 * DIN;

  prep_split<<<dim3(256), 256, 0, stream>>>(Wmlp, mhi, mlo, Wih_f, fhi, flo, Wih_b, bhi2, blo2);

  dim3 gG(MCH / 128, 12);
  for (int ci = 0; ci < NCH; ++ci) {
    gx_gemm_chunk<<<gG, 256, 0, stream>>>(seq, fhi, flo, bhi2, blo2, bih_f, bih_b,
                                          bufF, bufB, ci, NCH - 1 - ci);
    gru_scan_mfma<<<dim3(2 * NGRPS), 512, 0, stream>>>(
        lens, Whh_f, Whh_b, bhh_f, bhh_b, bufF, bufB, hstate, rnn, ci);
  }
  mlp_score<<<dim3(MTOT / 128, 2), 256, 0, stream>>>(rnn, mhi, mlo, bmlp, ctx, scoresH);
  softmax_pool<<<dim3(BATCH), 256, 0, stream>>>(lens, scoresH, rnn, out);
}